// Round 1
// baseline (5206.055 us; speedup 1.0000x reference)
//
#include <hip/hip_runtime.h>

// NeuralMemory scan: B=4, S=256, H=128, EXP=2, DEPTH=2.
// Round 11: single-poll scan via layer-1 replication.
// Counters (R10): VALUBusy 2.0% (~33% per active CU), Occupancy 1.5%, HBM
// 0.26% -> latency-bound; serial chain = 3 cross-WG polls (agent-scope
// memory-side round trips) + 6 barriers per step. This round keeps the FULL
// layer-1 n-state in every WG's registers (128 VGPRs) so the bwd-gh1 and
// fwd-h2 ED-reductions become WG-local; only layer-0's fwd output crosses
// WGs -> ONE poll per step (was 3), 5 barriers (was 6). Layer-1 p0 streams
// from L2 (coalesced float4 rows) inside the publish->poll shadow. Poll
// slots ping-pong on step parity (deterministic overwrite safety: phase g+2
// publish is data-dependent on phase g+1 poll, which requires all WGs'
// phase-g reads). LDS arrays accessed at 16-float stride get +4 floats of
// pad per 16-block (padb) -> bank-conflict-free AND 16B-aligned for b128.

constexpr int HD  = 128;   // H
constexpr int SEQ = 256;   // S
constexpr int NB  = 4;     // B
constexpr int ED  = 256;   // H*EXP
constexpr int CW  = 64;    // layer-0 hidden units per WG (ED/NWG)
constexpr int NWG = 4;     // workgroups per batch

__device__ __forceinline__ float sigm(float x){ return 1.0f/(1.0f+__expf(-x)); }
__device__ __forceinline__ int padb(int x){ return x + ((x>>4)<<2); } // +4 per 16-block
__device__ __forceinline__ float4 ld4(const float* p){
  return *reinterpret_cast<const float4*>(p);
}

// ---------------- kernel 1: q/k/v + gate scalars (unchanged) ----------------
__global__ __launch_bounds__(128) void qkv_kernel(
    const float* __restrict__ x,
    const float* __restrict__ Wq, const float* __restrict__ Wk, const float* __restrict__ Wv,
    const float* __restrict__ w_lr, const float* __restrict__ b_lr,
    const float* __restrict__ w_fg, const float* __restrict__ b_fg,
    const float* __restrict__ w_mo, const float* __restrict__ b_mo,
    float* __restrict__ qb, float* __restrict__ kb, float* __restrict__ vb,
    float* __restrict__ thb, float* __restrict__ alb, float* __restrict__ etb)
{
  const int bs = blockIdx.x;          // b*SEQ + s
  const int o  = threadIdx.x;         // 0..127
  __shared__ float xl[HD];
  __shared__ float rb[HD];
  xl[o] = x[(size_t)bs*HD + o];
  __syncthreads();

  float aq=0.f, ak=0.f, av=0.f;
  #pragma unroll 8
  for (int i=0;i<HD;i++){
    float xi = xl[i];
    aq = fmaf(xi, Wq[i*HD+o], aq);
    ak = fmaf(xi, Wk[i*HD+o], ak);
    av = fmaf(xi, Wv[i*HD+o], av);
  }
  float sq_ = aq*sigm(aq);
  float sk_ = ak*sigm(ak);
  float sv_ = av*sigm(av);

  auto bsum = [&](float v)->float {
    rb[o] = v; __syncthreads();
    for (int st=64; st>0; st>>=1){
      if (o < st) rb[o] += rb[o+st];
      __syncthreads();
    }
    float r = rb[0];
    __syncthreads();
    return r;
  };

  float nq = bsum(sq_*sq_);
  float nk = bsum(sk_*sk_);
  float dl = bsum(xl[o]*w_lr[o]);
  float df = bsum(xl[o]*w_fg[o]);
  float dm = bsum(xl[o]*w_mo[o]);

  qb[(size_t)bs*HD+o] = sq_ / fmaxf(sqrtf(nq), 1e-12f);
  kb[(size_t)bs*HD+o] = sk_ / fmaxf(sqrtf(nk), 1e-12f);
  vb[(size_t)bs*HD+o] = sv_;
  if (o==0){
    thb[bs] = sigm(dl + b_lr[0]) * 0.01f;   // MAX_LR
    alb[bs] = sigm(df + b_fg[0]);
    etb[bs] = sigm(dm + b_mo[0]);
  }
}

// ---------------- kernel 2: the sequential scan ----------------
__global__ __launch_bounds__(512, 2) void scan_kernel(
    const float* __restrict__ w1_0g, const float* __restrict__ b1_0g,
    const float* __restrict__ w2_0g, const float* __restrict__ b2_0g,
    const float* __restrict__ mw1_0g, const float* __restrict__ mb1_0g,
    const float* __restrict__ mw2_0g, const float* __restrict__ mb2_0g,
    const float* __restrict__ w1_1g, const float* __restrict__ b1_1g,
    const float* __restrict__ w2_1g, const float* __restrict__ b2_1g,
    const float* __restrict__ mw1_1g, const float* __restrict__ mb1_1g,
    const float* __restrict__ mw2_1g, const float* __restrict__ mb2_1g,
    const float* __restrict__ qbuf, const float* __restrict__ kbuf, const float* __restrict__ vbuf,
    const float* __restrict__ thb, const float* __restrict__ alb, const float* __restrict__ etb,
    unsigned long long* __restrict__ red, float* __restrict__ out)
{
  const int bid = blockIdx.x;
  const int b   = bid & 3;     // batch
  const int wg  = bid >> 2;    // 0..3 within batch (layer-0 ED slice + out slice)
  const int tid = threadIdx.x;
  // layer-0 mapping (ED split 4 ways, as before)
  const int iG = tid & 31;
  const int jG = tid >> 5;
  const int i0 = iG*4;
  const int j0 = jG*4;
  const int c0 = wg*CW;
  // layer-1 mapping (full layer per WG): 16-wide i/o block x 4-wide j block
  const int oG = tid & 7;          // i/o block id (8 blocks of 16)
  const int i1 = oG*16;
  const int jB = (tid >> 3) & 63;  // j block id (64 blocks of 4)
  const int j1 = jB*4;
  const int w8 = tid >> 6;         // wave id 0..7

  __shared__ float pw1L0[16][512];   // 32 KB layer-0 w1 p0
  __shared__ float pw2L0[16][512];   // 32 KB layer-0 w2 p0
  __shared__ float redbuf[8][312];   // q half [0,156), k half [156,312)
  __shared__ float redA[8][156];     // gh1 per-wave partial rows
  __shared__ float h1q[156];
  __shared__ float h1k[2][156];      // parity ping-pong (old needed in shadow)
  __shared__ float h2k[156];
  __shared__ float vS[2][156];       // v_t stash, parity ping-pong
  __shared__ float b1n0[CW], b1p0[CW], b2n0[32], b2p0[32];
  __shared__ float b1n1[256], b1p1[256], b2n1[128], b2p1[128];

  // n-form weights in registers: n = p0*(1-a)+m ; n_t = et*n + cP*p0 - th*g
  float nw1_0[16], nw2_0[16];  // layer-0 slice: (i0+ii, c0+j0+jj) / (c0+j0+jj, i0+oo)
  float nw1_1[64];             // layer-1 w1 FULL: [ii*4+jj] = (i1+ii, j1+jj)
  float nw2_1[64];             // layer-1 w2 FULL: [jj*16+oo] = (j1+jj, i1+oo)

  // ---------------- init ----------------
  {
#pragma unroll
    for (int jj=0;jj<4;jj++){
#pragma unroll
      for (int ii=0;ii<4;ii++){
        int gi1 = (i0+ii)*ED + (c0+j0+jj);
        float p1 = w1_0g[gi1];
        pw1L0[jj*4+ii][tid] = p1;
        nw1_0[jj*4+ii] = p1 + mw1_0g[gi1];
        int gi2 = (c0+j0+jj)*HD + (i0+ii);
        float p2 = w2_0g[gi2];
        pw2L0[jj*4+ii][tid] = p2;
        nw2_0[jj*4+ii] = p2 + mw2_0g[gi2];
      }
    }
#pragma unroll
    for (int ii=0;ii<16;ii++){
#pragma unroll
      for (int jj=0;jj<4;jj++){
        int gi = (i1+ii)*ED + (j1+jj);
        nw1_1[ii*4+jj] = w1_1g[gi] + mw1_1g[gi];
      }
    }
#pragma unroll
    for (int jj=0;jj<4;jj++){
#pragma unroll
      for (int oo=0;oo<16;oo++){
        int gi = (j1+jj)*HD + (i1+oo);
        nw2_1[jj*16+oo] = w2_1g[gi] + mw2_1g[gi];
      }
    }
  }
  if (tid < CW){
    float pa = b1_0g[c0+tid];
    b1p0[tid] = pa; b1n0[tid] = pa + mb1_0g[c0+tid];
  } else if (tid < CW+32){
    int oo = tid - CW;
    float pa = b2_0g[wg*32+oo];
    b2p0[oo] = pa; b2n0[oo] = pa + mb2_0g[wg*32+oo];
  }
  if (tid < 256){
    float pa = b1_1g[tid];
    b1p1[tid] = pa; b1n1[tid] = pa + mb1_1g[tid];
  } else if (tid < 384){
    int oo = tid - 256;
    float pa = b2_1g[oo];
    b2p1[oo] = pa; b2n1[oo] = pa + mb2_1g[oo];
  }

  // single-type poll slots, parity ping-pong: [b][par][wg][256]
  auto pubstore = [&](int par, unsigned seq, int idx, float val){
    unsigned long long* p = red + (((b*2+par)*NWG + wg)*256 + idx);
    unsigned long long pk = ((unsigned long long)seq << 32) |
                            (unsigned long long)__float_as_uint(val);
    __hip_atomic_store(p, pk, __ATOMIC_RELAXED, __HIP_MEMORY_SCOPE_AGENT);
  };
  auto pollacc = [&](int par, unsigned seq, int idx, float own)->float{
    unsigned long long* base = red + ((b*2+par)*NWG)*256;
    const int wA=((wg+1)&3)*256+idx, wB=((wg+2)&3)*256+idx, wC=((wg+3)&3)*256+idx;
    unsigned long long vA = __hip_atomic_load(base+wA, __ATOMIC_RELAXED, __HIP_MEMORY_SCOPE_AGENT);
    unsigned long long vB = __hip_atomic_load(base+wB, __ATOMIC_RELAXED, __HIP_MEMORY_SCOPE_AGENT);
    unsigned long long vC = __hip_atomic_load(base+wC, __ATOMIC_RELAXED, __HIP_MEMORY_SCOPE_AGENT);
    float s = own; unsigned got = 0;
    while (got != 7u){
      if (!(got&1u)){
        if ((unsigned)(vA>>32)==seq){ s += __uint_as_float((unsigned)vA); got|=1u; }
        else vA = __hip_atomic_load(base+wA, __ATOMIC_RELAXED, __HIP_MEMORY_SCOPE_AGENT);
      }
      if (!(got&2u)){
        if ((unsigned)(vB>>32)==seq){ s += __uint_as_float((unsigned)vB); got|=2u; }
        else vB = __hip_atomic_load(base+wB, __ATOMIC_RELAXED, __HIP_MEMORY_SCOPE_AGENT);
      }
      if (!(got&4u)){
        if ((unsigned)(vC>>32)==seq){ s += __uint_as_float((unsigned)vC); got|=4u; }
        else vC = __hip_atomic_load(base+wC, __ATOMIC_RELAXED, __HIP_MEMORY_SCOPE_AGENT);
      }
    }
    return s;
  };

  // loop-carried per-thread state
  float u1_r[4];       // layer-0 k-path preact (this WG's j slice)
  float u2_r[4];       // layer-1 k-path preact (this thread's j1 block)
  float kprev4[4];     // k_t at i0 range
  float v_r[4];        // v_t at i0 range
  float th_=0.f, et_=0.f, cP_=0.f;
  float gu2_r[4];      // layer-1 preact grad (needed in shadow)

  // forward from layer-0 preacts uq/uk. ro = residual (tid<128: q_t; else k_{t+1}).
  auto fwd = [&](int g, bool writeOut, bool doUpd,
                 const float* uq, const float* uk, float ro){
    const int t   = g - 1;
    const int par = g & 1;
    const unsigned seq = (unsigned)(g + 1);
    // layer-0 silu + out partials (weights already n_t)
    float s1qv[4], s1kv[4];
#pragma unroll
    for (int jj=0;jj<4;jj++){
      float a=uq[jj], c=uk[jj];
      s1qv[jj]=a*sigm(a); s1kv[jj]=c*sigm(c);
    }
    float oq[4]={0,0,0,0}, ok[4]={0,0,0,0};
#pragma unroll
    for (int jj=0;jj<4;jj++){
#pragma unroll
      for (int oo=0;oo<4;oo++){
        float w = nw2_0[jj*4+oo];
        oq[oo] = fmaf(s1qv[jj], w, oq[oo]);
        ok[oo] = fmaf(s1kv[jj], w, ok[oo]);
      }
    }
#pragma unroll
    for (int oo=0;oo<4;oo++){
      oq[oo] += __shfl_xor(oq[oo], 32, 64);
      ok[oo] += __shfl_xor(ok[oo], 32, 64);
    }
    if (!(tid & 32)){
      const int wv = tid >> 6;
#pragma unroll
      for (int oo=0;oo<4;oo++){
        redbuf[wv][padb(i0)+oo]     = oq[oo];
        redbuf[wv][156+padb(i0)+oo] = ok[oo];
      }
    }
    __syncthreads();                               // S_B
    const int o_ = tid & 127, half = tid >> 7;
    float pown = 0.f;
    if (tid < 256){
#pragma unroll
      for (int w_=0; w_<8; w_++) pown += redbuf[w_][half*156 + padb(o_)];
      if (o_ >= wg*32 && o_ < wg*32+32) pown += b2n0[o_ - wg*32];
      pubstore(par, seq, tid, pown);               // publish ASAP
    }
    if (doUpd){
      // ---------- publish->poll SHADOW: layer-1 updates + prefetch ----------
      const int rp = par ^ 1;                      // parity holding step-t state
      // w1[1] n-update; p0 streamed from L2, 8 rows in flight
      {
        const float* wr = w1_1g + (size_t)i1*ED + j1;
        float4 P[8];
        float hk8[8];
#pragma unroll
        for (int r2=0;r2<8;r2++) P[r2] = ld4(wr + (size_t)r2*ED);
#pragma unroll
        for (int r=0;r<2;r++){
          float4 hv = ld4(&h1k[rp][padb(i1)+r*4]);
          hk8[r*4+0]=hv.x; hk8[r*4+1]=hv.y; hk8[r*4+2]=hv.z; hk8[r*4+3]=hv.w;
        }
#pragma unroll
        for (int r2=0;r2<8;r2++){
          float pv[4]={P[r2].x,P[r2].y,P[r2].z,P[r2].w};
          float hk = hk8[r2];
#pragma unroll
          for (int jj=0;jj<4;jj++)
            nw1_1[r2*4+jj] = fmaf(et_, nw1_1[r2*4+jj],
                                  fmaf(cP_, pv[jj], -th_*(hk*gu2_r[jj])));
        }
#pragma unroll
        for (int r2=0;r2<8;r2++) P[r2] = ld4(wr + (size_t)(8+r2)*ED);
#pragma unroll
        for (int r=0;r<2;r++){
          float4 hv = ld4(&h1k[rp][padb(i1)+8+r*4]);
          hk8[r*4+0]=hv.x; hk8[r*4+1]=hv.y; hk8[r*4+2]=hv.z; hk8[r*4+3]=hv.w;
        }
#pragma unroll
        for (int r2=0;r2<8;r2++){
          float pv[4]={P[r2].x,P[r2].y,P[r2].z,P[r2].w};
          float hk = hk8[r2];
#pragma unroll
          for (int jj=0;jj<4;jj++)
            nw1_1[(8+r2)*4+jj] = fmaf(et_, nw1_1[(8+r2)*4+jj],
                                      fmaf(cP_, pv[jj], -th_*(hk*gu2_r[jj])));
        }
      }
      // w2[1] n-update
      {
        float g2v16[16];
        const float* vSt = vS[rp];
#pragma unroll
        for (int r=0;r<4;r++){
          float4 hv = ld4(&h2k[padb(i1)+r*4]);
          float4 vv = ld4(&vSt[padb(i1)+r*4]);
          g2v16[r*4+0]=0.015625f*(hv.x-vv.x);
          g2v16[r*4+1]=0.015625f*(hv.y-vv.y);
          g2v16[r*4+2]=0.015625f*(hv.z-vv.z);
          g2v16[r*4+3]=0.015625f*(hv.w-vv.w);
        }
        float s2ko[4];
#pragma unroll
        for (int jj=0;jj<4;jj++){ float u=u2_r[jj]; s2ko[jj]=u*sigm(u); }
        const float* wr2 = w2_1g + (size_t)j1*HD + i1;
        float4 P[8];
#pragma unroll
        for (int k2=0;k2<8;k2++) P[k2] = ld4(wr2 + (k2>>2)*HD + (k2&3)*4);
#pragma unroll
        for (int k2=0;k2<8;k2++){
          float pv[4]={P[k2].x,P[k2].y,P[k2].z,P[k2].w};
          const int jj=k2>>2, qq=k2&3;
#pragma unroll
          for (int m=0;m<4;m++)
            nw2_1[jj*16+qq*4+m] = fmaf(et_, nw2_1[jj*16+qq*4+m],
                                       fmaf(cP_, pv[m], -th_*(s2ko[jj]*g2v16[qq*4+m])));
        }
#pragma unroll
        for (int k2=0;k2<8;k2++) P[k2] = ld4(wr2 + (2+(k2>>2))*HD + (k2&3)*4);
#pragma unroll
        for (int k2=0;k2<8;k2++){
          float pv[4]={P[k2].x,P[k2].y,P[k2].z,P[k2].w};
          const int jj=2+(k2>>2), qq=k2&3;
#pragma unroll
          for (int m=0;m<4;m++)
            nw2_1[jj*16+qq*4+m] = fmaf(et_, nw2_1[jj*16+qq*4+m],
                                       fmaf(cP_, pv[m], -th_*(s2ko[jj]*g2v16[qq*4+m])));
        }
        if (tid < 128){
          float g2vt = 0.015625f*(h2k[padb(tid)] - vSt[padb(tid)]);
          b2n1[tid] = fmaf(et_, b2n1[tid], fmaf(cP_, b2p1[tid], -th_*g2vt));
        }
      }
      if ((tid & 7) == 0){
#pragma unroll
        for (int jj=0;jj<4;jj++)
          b1n1[j1+jj] = fmaf(et_, b1n1[j1+jj], fmaf(cP_, b1p1[j1+jj], -th_*gu2_r[jj]));
      }
      // prefetch v_{t+1}
      const int tn2 = (t < SEQ-1) ? t+1 : SEQ-1;
#pragma unroll
      for (int ii=0;ii<4;ii++) v_r[ii] = vbuf[((size_t)b*SEQ + tn2)*HD + i0+ii];
      if (tid < 128) vS[par][padb(tid)] = vbuf[((size_t)b*SEQ + tn2)*HD + tid];
    }
    // ---------- the ONE poll ----------
    if (tid < 256){
      float s0 = ro + pollacc(par, seq, tid, pown);
      if (tid < 128) h1q[padb(o_)] = s0;
      else           h1k[par][padb(o_)] = s0;
    }
    __syncthreads();                               // S_C
    // ---------- layer-1 forward (local, n_t) ----------
    float u2q[4]={0,0,0,0}, u2k[4]={0,0,0,0};
#pragma unroll
    for (int r=0;r<4;r++){
      float4 hv = ld4(&h1q[padb(i1)+r*4]);
      float hvv[4]={hv.x,hv.y,hv.z,hv.w};
#pragma unroll
      for (int m=0;m<4;m++){
        float h_ = hvv[m];
#pragma unroll
        for (int jj=0;jj<4;jj++)
          u2q[jj] = fmaf(h_, nw1_1[(r*4+m)*4+jj], u2q[jj]);
      }
    }
    {
      const float* h1kn = h1k[par];
#pragma unroll
      for (int r=0;r<4;r++){
        float4 hv = ld4(&h1kn[padb(i1)+r*4]);
        float hvv[4]={hv.x,hv.y,hv.z,hv.w};
#pragma unroll
        for (int m=0;m<4;m++){
          float h_ = hvv[m];
#pragma unroll
          for (int jj=0;jj<4;jj++)
            u2k[jj] = fmaf(h_, nw1_1[(r*4+m)*4+jj], u2k[jj]);
        }
      }
    }
#pragma unroll
    for (int d=1; d<8; d<<=1){
#pragma unroll
      for (int jj=0;jj<4;jj++){
        u2q[jj] += __shfl_xor(u2q[jj], d, 64);
        u2k[jj] += __shfl_xor(u2k[jj], d, 64);
      }
    }
    float s2q[4], s2k[4];
#pragma unroll
    for (int jj=0;jj<4;jj++){
      float bb = b1n1[j1+jj];
      float a = u2q[jj] + bb, c = u2k[jj] + bb;
      u2_r[jj] = c;
      s2q[jj] = a*sigm(a);
      s2k[jj] = c*sigm(c);
    }
    // layer-1 out partials: q path then k path (caps register pressure)
    {
      float ho[16];
#pragma unroll
      for (int oo=0;oo<16;oo++) ho[oo]=0.f;
#pragma unroll
      for (int jj=0;jj<4;jj++){
        float s_ = s2q[jj];
#pragma unroll
        for (int oo=0;oo<16;oo++) ho[oo] = fmaf(s_, nw2_1[jj*16+oo], ho[oo]);
      }
#pragma unroll
      for (int d=8; d<64; d<<=1){
#pragma unroll
        for (int oo=0;oo<16;oo++) ho[oo] += __shfl_xor(ho[oo], d, 64);
      }
      if ((tid&56)==0){
#pragma unroll
        for (int r=0;r<4;r++){
          float4 s; s.x=ho[r*4]; s.y=ho[r*4+1]; s.z=ho[r*4+2]; s.w=ho[r*4+3];
          *reinterpret_cast<float4*>(&redbuf[w8][padb(i1)+r*4]) = s;
        }
      }
#pragma unroll
      for (int oo=0;oo<16;oo++) ho[oo]=0.f;
#pragma unroll
      for (int jj=0;jj<4;jj++){
        float s_ = s2k[jj];
#pragma unroll
        for (int oo=0;oo<16;oo++) ho[oo] = fmaf(s_, nw2_1[jj*16+oo], ho[oo]);
      }
#pragma unroll
      for (int d=8; d<64; d<<=1){
#pragma unroll
        for (int oo=0;oo<16;oo++) ho[oo] += __shfl_xor(ho[oo], d, 64);
      }
      if ((tid&56)==0){
#pragma unroll
        for (int r=0;r<4;r++){
          float4 s; s.x=ho[r*4]; s.y=ho[r*4+1]; s.z=ho[r*4+2]; s.w=ho[r*4+3];
          *reinterpret_cast<float4*>(&redbuf[w8][156+padb(i1)+r*4]) = s;
        }
      }
    }
    __syncthreads();                               // S_D
    if (tid < 256){
      float s = 0.f;
#pragma unroll
      for (int w_=0; w_<8; w_++) s += redbuf[w_][half*156 + padb(o_)];
      s += b2n1[o_];
      if (tid < 128){
        if (writeOut && o_ >= wg*32 && o_ < wg*32+32)
          out[((size_t)(b*SEQ + t))*HD + o_] = h1q[padb(o_)] + s;
      } else {
        h2k[padb(o_)] = h1k[par][padb(o_)] + s;
      }
    }
  };

  // ---- prologue: forward k_0 with n_{-1} = p0 + m0 ----
  {
#pragma unroll
    for (int ii=0;ii<4;ii++){
      kprev4[ii] = kbuf[((size_t)b*SEQ + 0)*HD + i0+ii];
      v_r[ii]    = vbuf[((size_t)b*SEQ + 0)*HD + i0+ii];
    }
    if (tid < 128) vS[0][padb(tid)] = vbuf[((size_t)b*SEQ + 0)*HD + tid];
    float ro0 = 0.f;
    if (tid >= 128 && tid < 256)
      ro0 = kbuf[((size_t)b*SEQ + 0)*HD + (tid-128)];
    __syncthreads();   // init (LDS p0/biases/vS) visible
    float ak0[4]={0,0,0,0};
#pragma unroll
    for (int ii=0;ii<4;ii++){
      float ki = kprev4[ii];
#pragma unroll
      for (int jj=0;jj<4;jj++) ak0[jj] = fmaf(ki, nw1_0[jj*4+ii], ak0[jj]);
    }
#pragma unroll
    for (int d=1; d<32; d<<=1){
#pragma unroll
      for (int jj=0;jj<4;jj++) ak0[jj] += __shfl_xor(ak0[jj], d, 64);
    }
    float uq0[4], uk0[4];
#pragma unroll
    for (int jj=0;jj<4;jj++){
      float bb = b1n0[j0+jj];
      uq0[jj] = bb;              // q-path dummy (discarded, finite)
      uk0[jj] = ak0[jj] + bb;
      u1_r[jj] = uk0[jj];
    }
    fwd(0, false, false, uq0, uk0, ro0);   // par=0, seq=1
  }

  float dPrev = 1.f;   // 1 - alpha_{-1}
  for (int t=0; t<SEQ; ++t){
    const int g  = t+1;
    const int tn = (t < SEQ-1) ? t+1 : SEQ-1;
    __syncthreads();                       // S_E: h2k/u2 state from prev fwd visible
    // ---- P1: loads (latency hidden under bwd compute) ----
    float qv4[4], kv4[4];
#pragma unroll
    for (int ii=0;ii<4;ii++){
      qv4[ii] = qbuf[((size_t)b*SEQ + t )*HD + i0+ii];
      kv4[ii] = kbuf[((size_t)b*SEQ + tn)*HD + i0+ii];
    }
    float ro = 0.f;
    if (tid < 128)      ro = qbuf[((size_t)b*SEQ + t )*HD + tid];
    else if (tid < 256) ro = kbuf[((size_t)b*SEQ + tn)*HD + (tid-128)];
    th_ = thb[b*SEQ+t];
    const float al = alb[b*SEQ+t];
    et_ = etb[b*SEQ+t];
    const float dcur = 1.f - al;
    cP_ = dcur - et_*dPrev;
    // ---- P2: g2v at layer-0 range ----
    float g2v_r[4];
    {
      float4 hh = ld4(&h2k[padb(i0)]);
      g2v_r[0]=0.015625f*(hh.x-v_r[0]); g2v_r[1]=0.015625f*(hh.y-v_r[1]);
      g2v_r[2]=0.015625f*(hh.z-v_r[2]); g2v_r[3]=0.015625f*(hh.w-v_r[3]);
    }
    // ---- P3: gu2 (weights n_{t-1}) — fully local now ----
    {
      const float* vSt = vS[t&1];
      float acc2[4]={0,0,0,0};
#pragma unroll
      for (int r=0;r<4;r++){
        float4 hv = ld4(&h2k[padb(i1)+r*4]);
        float4 vv = ld4(&vSt[padb(i1)+r*4]);
        float gv[4] = {0.015625f*(hv.x-vv.x), 0.015625f*(hv.y-vv.y),
                       0.015625f*(hv.z-vv.z), 0.015625f*(hv.w-vv.w)};
#pragma unroll
        for (int m=0;m<4;m++){
#pragma unroll
          for (int jj=0;jj<4;jj++)
            acc2[jj] = fmaf(gv[m], nw2_1[jj*16+r*4+m], acc2[jj]);
        }
      }
#pragma unroll
      for (int d=1; d<8; d<<=1){
#pragma unroll
        for (int jj=0;jj<4;jj++) acc2[jj] += __shfl_xor(acc2[jj], d, 64);
      }
#pragma unroll
      for (int jj=0;jj<4;jj++){
        float u = u2_r[jj]; float sg = sigm(u);
        gu2_r[jj] = acc2[jj]*sg*fmaf(u, 1.f-sg, 1.f);
      }
    }
    // ---- P4: gh1 partials over FULL ED (local; cross-wave via redA) ----
    {
      float a2[16];
#pragma unroll
      for (int ii=0;ii<16;ii++) a2[ii]=0.f;
#pragma unroll
      for (int jj=0;jj<4;jj++){
        float gj = gu2_r[jj];
#pragma unroll
        for (int ii=0;ii<16;ii++) a2[ii] = fmaf(gj, nw1_1[ii*4+jj], a2[ii]);
      }
#pragma unroll
      for (int d=8; d<64; d<<=1){
#pragma unroll
        for (int ii=0;ii<16;ii++) a2[ii] += __shfl_xor(a2[ii], d, 64);
      }
      if ((tid&56)==0){
#pragma unroll
        for (int r=0;r<4;r++){
          float4 s; s.x=a2[r*4]; s.y=a2[r*4+1]; s.z=a2[r*4+2]; s.w=a2[r*4+3];
          *reinterpret_cast<float4*>(&redA[w8][padb(i1)+r*4]) = s;
        }
      }
    }
    __syncthreads();                       // S_A
    // ---- P5: gh1 at own indices (per-thread 8-row sum; no extra barrier) ----
    float gh1_r[4];
    {
      float sx=g2v_r[0], sy=g2v_r[1], sz=g2v_r[2], sw=g2v_r[3];
#pragma unroll
      for (int w_=0; w_<8; w_++){
        float4 rr = ld4(&redA[w_][padb(i0)]);
        sx+=rr.x; sy+=rr.y; sz+=rr.z; sw+=rr.w;
      }
      gh1_r[0]=sx; gh1_r[1]=sy; gh1_r[2]=sz; gh1_r[3]=sw;
    }
    float gu1r[4];
    {
      float acc1[4]={0,0,0,0};
#pragma unroll
      for (int oo=0;oo<4;oo++){
        float go = gh1_r[oo];
#pragma unroll
        for (int jj=0;jj<4;jj++) acc1[jj] = fmaf(go, nw2_0[jj*4+oo], acc1[jj]);
      }
#pragma unroll
      for (int d=1; d<32; d<<=1){
#pragma unroll
        for (int jj=0;jj<4;jj++) acc1[jj] += __shfl_xor(acc1[jj], d, 64);
      }
#pragma unroll
      for (int jj=0;jj<4;jj++){
        float u = u1_r[jj]; float sg = sigm(u);
        gu1r[jj] = acc1[jj]*sg*fmaf(u, 1.f-sg, 1.f);
      }
    }
    // ---- P6: layer-0 n-updates (LDS p0) ----
    {
      float s1ko[4];
#pragma unroll
      for (int jj=0;jj<4;jj++){ float u=u1_r[jj]; s1ko[jj]=u*sigm(u); }
#pragma unroll
      for (int jj=0;jj<4;jj++){
#pragma unroll
        for (int ii=0;ii<4;ii++){
          int e = jj*4+ii;
          nw1_0[e] = fmaf(et_, nw1_0[e], fmaf(cP_, pw1L0[e][tid], -th_*(kprev4[ii]*gu1r[jj])));
          nw2_0[e] = fmaf(et_, nw2_0[e], fmaf(cP_, pw2L0[e][tid], -th_*(s1ko[jj]*gh1_r[ii])));
        }
      }
      if (iG==0){
#pragma unroll
        for (int jj=0;jj<4;jj++)
          b1n0[j0+jj] = fmaf(et_, b1n0[j0+jj], fmaf(cP_, b1p0[j0+jj], -th_*gu1r[jj]));
      }
      if (jG==0 && iG>=wg*8 && iG<wg*8+8){
#pragma unroll
        for (int ii=0;ii<4;ii++)
          b2n0[i0+ii-wg*32] = fmaf(et_, b2n0[i0+ii-wg*32],
                                   fmaf(cP_, b2p0[i0+ii-wg*32], -th_*gh1_r[ii]));
      }
    }
    // ---- P7: layer-0 dual u with n_t ----
    float uqf[4], ukf[4];
    {
      float aq[4]={0,0,0,0}, ak[4]={0,0,0,0};
#pragma unroll
      for (int ii=0;ii<4;ii++){
        float qi = qv4[ii], ki = kv4[ii];
#pragma unroll
        for (int jj=0;jj<4;jj++){
          float w = nw1_0[jj*4+ii];
          aq[jj] = fmaf(qi, w, aq[jj]);
          ak[jj] = fmaf(ki, w, ak[jj]);
        }
      }
#pragma unroll
      for (int d=1; d<32; d<<=1){
#pragma unroll
        for (int jj=0;jj<4;jj++){
          aq[jj] += __shfl_xor(aq[jj], d, 64);
          ak[jj] += __shfl_xor(ak[jj], d, 64);
        }
      }
#pragma unroll
      for (int jj=0;jj<4;jj++){
        float bb = b1n0[j0+jj];   // wave-local RAW (writer iG==0 same wave)
        uqf[jj] = aq[jj] + bb;
        ukf[jj] = ak[jj] + bb;
      }
    }
#pragma unroll
    for (int ii=0;ii<4;ii++) kprev4[ii] = kv4[ii];
#pragma unroll
    for (int jj=0;jj<4;jj++) u1_r[jj] = ukf[jj];
    dPrev = dcur;
    fwd(g, true, true, uqf, ukf, ro);
  }
}

extern "C" void kernel_launch(void* const* d_in, const int* in_sizes, int n_in,
                              void* d_out, int out_size, void* d_ws, size_t ws_size,
                              hipStream_t stream)
{
  (void)in_sizes; (void)n_in; (void)out_size; (void)ws_size;
  const float* x    = (const float*)d_in[0];
  const float* Wq   = (const float*)d_in[1];
  const float* Wk   = (const float*)d_in[2];
  const float* Wv   = (const float*)d_in[3];
  const float* w_lr = (const float*)d_in[4];
  const float* b_lr = (const float*)d_in[5];
  const float* w_fg = (const float*)d_in[6];
  const float* b_fg = (const float*)d_in[7];
  const float* w_mo = (const float*)d_in[8];
  const float* b_mo = (const float*)d_in[9];
  const float* w1_0 = (const float*)d_in[10];
  const float* b1_0 = (const float*)d_in[11];
  const float* w2_0 = (const float*)d_in[12];
  const float* b2_0 = (const float*)d_in[13];
  const float* m_w1_0 = (const float*)d_in[14];
  const float* m_b1_0 = (const float*)d_in[15];
  const float* m_w2_0 = (const float*)d_in[16];
  const float* m_b2_0 = (const float*)d_in[17];
  const float* w1_1 = (const float*)d_in[18];
  const float* b1_1 = (const float*)d_in[19];
  const float* w2_1 = (const float*)d_in[20];
  const float* b2_1 = (const float*)d_in[21];
  const float* m_w1_1 = (const float*)d_in[22];
  const float* m_b1_1 = (const float*)d_in[23];
  const float* m_w2_1 = (const float*)d_in[24];
  const float* m_b2_1 = (const float*)d_in[25];

  float* wsf = (float*)d_ws;
  unsigned long long* red = (unsigned long long*)d_ws;   // 64 KB of slots ([b][par][wg][256])
  float* qbuf = wsf + 32768;
  float* kbuf = qbuf + NB*SEQ*HD;
  float* vbuf = kbuf + NB*SEQ*HD;
  float* thb  = vbuf + NB*SEQ*HD;
  float* alb  = thb + NB*SEQ;
  float* etb  = alb + NB*SEQ;
  // ws re-poisoned to 0xAA each launch; 0xAAAAAAAA is never a valid seq tag.

  qkv_kernel<<<dim3(NB*SEQ), dim3(HD), 0, stream>>>(
      x, Wq, Wk, Wv, w_lr, b_lr, w_fg, b_fg, w_mo, b_mo,
      qbuf, kbuf, vbuf, thb, alb, etb);

  scan_kernel<<<dim3(NB*NWG), dim3(512), 0, stream>>>(
      w1_0, b1_0, w2_0, b2_0, m_w1_0, m_b1_0, m_w2_0, m_b2_0,
      w1_1, b1_1, w2_1, b2_1, m_w1_1, m_b1_1, m_w2_1, m_b2_1,
      qbuf, kbuf, vbuf, thb, alb, etb,
      red, (float*)d_out);
}

// Round 2
// 5198.997 us; speedup vs baseline: 1.0014x; 1.0014x over previous
//
#include <hip/hip_runtime.h>

// NeuralMemory scan: B=4, S=256, H=128, EXP=2, DEPTH=2.
// Round 12: R11 (single-poll via layer-1 replication) + register-budget fix.
// R11 post-mortem: VGPR_Count stayed 128 while the design needs ~220 ->
// layer-1 weight state spilled to scratch; dur 2392 -> 5206 us, VALUBusy
// dropped 2.0 -> 1.5 (latency-on-spill signature; spill traffic L2-absorbed
// so FETCH/WRITE stayed flat). Fix: pin amdgpu_waves_per_eu(2,2) (256-VGPR
// budget, allocator may not chase higher occupancy) and chunk the p0-stream
// updates from float4 P[8] to P[4] batches to cut peak temp pressure.
// Structure (verified correct in R11): full layer-1 n-state per WG in regs
// -> bwd gh1 + fwd h2 reductions WG-local; ONE cross-WG poll per step
// (layer-0 fwd), 5 barriers; layer-1 p0 streamed from L2 in the poll shadow;
// poll slots ping-pong on step parity.

constexpr int HD  = 128;   // H
constexpr int SEQ = 256;   // S
constexpr int NB  = 4;     // B
constexpr int ED  = 256;   // H*EXP
constexpr int CW  = 64;    // layer-0 hidden units per WG (ED/NWG)
constexpr int NWG = 4;     // workgroups per batch

__device__ __forceinline__ float sigm(float x){ return 1.0f/(1.0f+__expf(-x)); }
__device__ __forceinline__ int padb(int x){ return x + ((x>>4)<<2); } // +4 per 16-block
__device__ __forceinline__ float4 ld4(const float* p){
  return *reinterpret_cast<const float4*>(p);
}

// ---------------- kernel 1: q/k/v + gate scalars (unchanged) ----------------
__global__ __launch_bounds__(128) void qkv_kernel(
    const float* __restrict__ x,
    const float* __restrict__ Wq, const float* __restrict__ Wk, const float* __restrict__ Wv,
    const float* __restrict__ w_lr, const float* __restrict__ b_lr,
    const float* __restrict__ w_fg, const float* __restrict__ b_fg,
    const float* __restrict__ w_mo, const float* __restrict__ b_mo,
    float* __restrict__ qb, float* __restrict__ kb, float* __restrict__ vb,
    float* __restrict__ thb, float* __restrict__ alb, float* __restrict__ etb)
{
  const int bs = blockIdx.x;          // b*SEQ + s
  const int o  = threadIdx.x;         // 0..127
  __shared__ float xl[HD];
  __shared__ float rb[HD];
  xl[o] = x[(size_t)bs*HD + o];
  __syncthreads();

  float aq=0.f, ak=0.f, av=0.f;
  #pragma unroll 8
  for (int i=0;i<HD;i++){
    float xi = xl[i];
    aq = fmaf(xi, Wq[i*HD+o], aq);
    ak = fmaf(xi, Wk[i*HD+o], ak);
    av = fmaf(xi, Wv[i*HD+o], av);
  }
  float sq_ = aq*sigm(aq);
  float sk_ = ak*sigm(ak);
  float sv_ = av*sigm(av);

  auto bsum = [&](float v)->float {
    rb[o] = v; __syncthreads();
    for (int st=64; st>0; st>>=1){
      if (o < st) rb[o] += rb[o+st];
      __syncthreads();
    }
    float r = rb[0];
    __syncthreads();
    return r;
  };

  float nq = bsum(sq_*sq_);
  float nk = bsum(sk_*sk_);
  float dl = bsum(xl[o]*w_lr[o]);
  float df = bsum(xl[o]*w_fg[o]);
  float dm = bsum(xl[o]*w_mo[o]);

  qb[(size_t)bs*HD+o] = sq_ / fmaxf(sqrtf(nq), 1e-12f);
  kb[(size_t)bs*HD+o] = sk_ / fmaxf(sqrtf(nk), 1e-12f);
  vb[(size_t)bs*HD+o] = sv_;
  if (o==0){
    thb[bs] = sigm(dl + b_lr[0]) * 0.01f;   // MAX_LR
    alb[bs] = sigm(df + b_fg[0]);
    etb[bs] = sigm(dm + b_mo[0]);
  }
}

// ---------------- kernel 2: the sequential scan ----------------
__global__ __launch_bounds__(512)
__attribute__((amdgpu_waves_per_eu(2, 2)))
void scan_kernel(
    const float* __restrict__ w1_0g, const float* __restrict__ b1_0g,
    const float* __restrict__ w2_0g, const float* __restrict__ b2_0g,
    const float* __restrict__ mw1_0g, const float* __restrict__ mb1_0g,
    const float* __restrict__ mw2_0g, const float* __restrict__ mb2_0g,
    const float* __restrict__ w1_1g, const float* __restrict__ b1_1g,
    const float* __restrict__ w2_1g, const float* __restrict__ b2_1g,
    const float* __restrict__ mw1_1g, const float* __restrict__ mb1_1g,
    const float* __restrict__ mw2_1g, const float* __restrict__ mb2_1g,
    const float* __restrict__ qbuf, const float* __restrict__ kbuf, const float* __restrict__ vbuf,
    const float* __restrict__ thb, const float* __restrict__ alb, const float* __restrict__ etb,
    unsigned long long* __restrict__ red, float* __restrict__ out)
{
  const int bid = blockIdx.x;
  const int b   = bid & 3;     // batch
  const int wg  = bid >> 2;    // 0..3 within batch (layer-0 ED slice + out slice)
  const int tid = threadIdx.x;
  // layer-0 mapping (ED split 4 ways, as before)
  const int iG = tid & 31;
  const int jG = tid >> 5;
  const int i0 = iG*4;
  const int j0 = jG*4;
  const int c0 = wg*CW;
  // layer-1 mapping (full layer per WG): 16-wide i/o block x 4-wide j block
  const int oG = tid & 7;          // i/o block id (8 blocks of 16)
  const int i1 = oG*16;
  const int jB = (tid >> 3) & 63;  // j block id (64 blocks of 4)
  const int j1 = jB*4;
  const int w8 = tid >> 6;         // wave id 0..7

  __shared__ float pw1L0[16][512];   // 32 KB layer-0 w1 p0
  __shared__ float pw2L0[16][512];   // 32 KB layer-0 w2 p0
  __shared__ float redbuf[8][312];   // q half [0,156), k half [156,312)
  __shared__ float redA[8][156];     // gh1 per-wave partial rows
  __shared__ float h1q[156];
  __shared__ float h1k[2][156];      // parity ping-pong (old needed in shadow)
  __shared__ float h2k[156];
  __shared__ float vS[2][156];       // v_t stash, parity ping-pong
  __shared__ float b1n0[CW], b1p0[CW], b2n0[32], b2p0[32];
  __shared__ float b1n1[256], b1p1[256], b2n1[128], b2p1[128];

  // n-form weights in registers: n = p0*(1-a)+m ; n_t = et*n + cP*p0 - th*g
  float nw1_0[16], nw2_0[16];  // layer-0 slice: (i0+ii, c0+j0+jj) / (c0+j0+jj, i0+oo)
  float nw1_1[64];             // layer-1 w1 FULL: [ii*4+jj] = (i1+ii, j1+jj)
  float nw2_1[64];             // layer-1 w2 FULL: [jj*16+oo] = (j1+jj, i1+oo)

  // ---------------- init ----------------
  {
#pragma unroll
    for (int jj=0;jj<4;jj++){
#pragma unroll
      for (int ii=0;ii<4;ii++){
        int gi1 = (i0+ii)*ED + (c0+j0+jj);
        float p1 = w1_0g[gi1];
        pw1L0[jj*4+ii][tid] = p1;
        nw1_0[jj*4+ii] = p1 + mw1_0g[gi1];
        int gi2 = (c0+j0+jj)*HD + (i0+ii);
        float p2 = w2_0g[gi2];
        pw2L0[jj*4+ii][tid] = p2;
        nw2_0[jj*4+ii] = p2 + mw2_0g[gi2];
      }
    }
#pragma unroll
    for (int ii=0;ii<16;ii++){
#pragma unroll
      for (int jj=0;jj<4;jj++){
        int gi = (i1+ii)*ED + (j1+jj);
        nw1_1[ii*4+jj] = w1_1g[gi] + mw1_1g[gi];
      }
    }
#pragma unroll
    for (int jj=0;jj<4;jj++){
#pragma unroll
      for (int oo=0;oo<16;oo++){
        int gi = (j1+jj)*HD + (i1+oo);
        nw2_1[jj*16+oo] = w2_1g[gi] + mw2_1g[gi];
      }
    }
  }
  if (tid < CW){
    float pa = b1_0g[c0+tid];
    b1p0[tid] = pa; b1n0[tid] = pa + mb1_0g[c0+tid];
  } else if (tid < CW+32){
    int oo = tid - CW;
    float pa = b2_0g[wg*32+oo];
    b2p0[oo] = pa; b2n0[oo] = pa + mb2_0g[wg*32+oo];
  }
  if (tid < 256){
    float pa = b1_1g[tid];
    b1p1[tid] = pa; b1n1[tid] = pa + mb1_1g[tid];
  } else if (tid < 384){
    int oo = tid - 256;
    float pa = b2_1g[oo];
    b2p1[oo] = pa; b2n1[oo] = pa + mb2_1g[oo];
  }

  // single-type poll slots, parity ping-pong: [b][par][wg][256]
  auto pubstore = [&](int par, unsigned seq, int idx, float val){
    unsigned long long* p = red + (((b*2+par)*NWG + wg)*256 + idx);
    unsigned long long pk = ((unsigned long long)seq << 32) |
                            (unsigned long long)__float_as_uint(val);
    __hip_atomic_store(p, pk, __ATOMIC_RELAXED, __HIP_MEMORY_SCOPE_AGENT);
  };
  auto pollacc = [&](int par, unsigned seq, int idx, float own)->float{
    unsigned long long* base = red + ((b*2+par)*NWG)*256;
    const int wA=((wg+1)&3)*256+idx, wB=((wg+2)&3)*256+idx, wC=((wg+3)&3)*256+idx;
    unsigned long long vA = __hip_atomic_load(base+wA, __ATOMIC_RELAXED, __HIP_MEMORY_SCOPE_AGENT);
    unsigned long long vB = __hip_atomic_load(base+wB, __ATOMIC_RELAXED, __HIP_MEMORY_SCOPE_AGENT);
    unsigned long long vC = __hip_atomic_load(base+wC, __ATOMIC_RELAXED, __HIP_MEMORY_SCOPE_AGENT);
    float s = own; unsigned got = 0;
    while (got != 7u){
      if (!(got&1u)){
        if ((unsigned)(vA>>32)==seq){ s += __uint_as_float((unsigned)vA); got|=1u; }
        else vA = __hip_atomic_load(base+wA, __ATOMIC_RELAXED, __HIP_MEMORY_SCOPE_AGENT);
      }
      if (!(got&2u)){
        if ((unsigned)(vB>>32)==seq){ s += __uint_as_float((unsigned)vB); got|=2u; }
        else vB = __hip_atomic_load(base+wB, __ATOMIC_RELAXED, __HIP_MEMORY_SCOPE_AGENT);
      }
      if (!(got&4u)){
        if ((unsigned)(vC>>32)==seq){ s += __uint_as_float((unsigned)vC); got|=4u; }
        else vC = __hip_atomic_load(base+wC, __ATOMIC_RELAXED, __HIP_MEMORY_SCOPE_AGENT);
      }
    }
    return s;
  };

  // loop-carried per-thread state
  float u1_r[4];       // layer-0 k-path preact (this WG's j slice)
  float u2_r[4];       // layer-1 k-path preact (this thread's j1 block)
  float kprev4[4];     // k_t at i0 range
  float v_r[4];        // v_t at i0 range
  float th_=0.f, et_=0.f, cP_=0.f;
  float gu2_r[4];      // layer-1 preact grad (needed in shadow)

  // forward from layer-0 preacts uq/uk. ro = residual (tid<128: q_t; else k_{t+1}).
  auto fwd = [&](int g, bool writeOut, bool doUpd,
                 const float* uq, const float* uk, float ro){
    const int t   = g - 1;
    const int par = g & 1;
    const unsigned seq = (unsigned)(g + 1);
    // layer-0 silu + out partials (weights already n_t)
    float s1qv[4], s1kv[4];
#pragma unroll
    for (int jj=0;jj<4;jj++){
      float a=uq[jj], c=uk[jj];
      s1qv[jj]=a*sigm(a); s1kv[jj]=c*sigm(c);
    }
    float oq[4]={0,0,0,0}, ok[4]={0,0,0,0};
#pragma unroll
    for (int jj=0;jj<4;jj++){
#pragma unroll
      for (int oo=0;oo<4;oo++){
        float w = nw2_0[jj*4+oo];
        oq[oo] = fmaf(s1qv[jj], w, oq[oo]);
        ok[oo] = fmaf(s1kv[jj], w, ok[oo]);
      }
    }
#pragma unroll
    for (int oo=0;oo<4;oo++){
      oq[oo] += __shfl_xor(oq[oo], 32, 64);
      ok[oo] += __shfl_xor(ok[oo], 32, 64);
    }
    if (!(tid & 32)){
      const int wv = tid >> 6;
#pragma unroll
      for (int oo=0;oo<4;oo++){
        redbuf[wv][padb(i0)+oo]     = oq[oo];
        redbuf[wv][156+padb(i0)+oo] = ok[oo];
      }
    }
    __syncthreads();                               // S_B
    const int o_ = tid & 127, half = tid >> 7;
    float pown = 0.f;
    if (tid < 256){
#pragma unroll
      for (int w_=0; w_<8; w_++) pown += redbuf[w_][half*156 + padb(o_)];
      if (o_ >= wg*32 && o_ < wg*32+32) pown += b2n0[o_ - wg*32];
      pubstore(par, seq, tid, pown);               // publish ASAP
    }
    if (doUpd){
      // ---------- publish->poll SHADOW: layer-1 updates + prefetch ----------
      const int rp = par ^ 1;                      // parity holding step-t state
      // w1[1] n-update; p0 streamed from L2, 4 rows per batch (VGPR cap)
      {
        const float* wr = w1_1g + (size_t)i1*ED + j1;
#pragma unroll
        for (int bt=0; bt<4; bt++){
          float4 P[4];
#pragma unroll
          for (int r2=0;r2<4;r2++) P[r2] = ld4(wr + (size_t)(bt*4+r2)*ED);
          float4 hv = ld4(&h1k[rp][padb(i1)+bt*4]);
          float hk4[4] = {hv.x, hv.y, hv.z, hv.w};
#pragma unroll
          for (int r2=0;r2<4;r2++){
            float pv[4]={P[r2].x,P[r2].y,P[r2].z,P[r2].w};
            float hk = hk4[r2];
#pragma unroll
            for (int jj=0;jj<4;jj++)
              nw1_1[(bt*4+r2)*4+jj] = fmaf(et_, nw1_1[(bt*4+r2)*4+jj],
                                           fmaf(cP_, pv[jj], -th_*(hk*gu2_r[jj])));
          }
        }
      }
      // w2[1] n-update; 4 float4 p0 loads per jj row
      {
        float g2v16[16];
        const float* vSt = vS[rp];
#pragma unroll
        for (int r=0;r<4;r++){
          float4 hv = ld4(&h2k[padb(i1)+r*4]);
          float4 vv = ld4(&vSt[padb(i1)+r*4]);
          g2v16[r*4+0]=0.015625f*(hv.x-vv.x);
          g2v16[r*4+1]=0.015625f*(hv.y-vv.y);
          g2v16[r*4+2]=0.015625f*(hv.z-vv.z);
          g2v16[r*4+3]=0.015625f*(hv.w-vv.w);
        }
        const float* wr2 = w2_1g + (size_t)j1*HD + i1;
#pragma unroll
        for (int jj=0;jj<4;jj++){
          float4 P[4];
#pragma unroll
          for (int qq=0;qq<4;qq++) P[qq] = ld4(wr2 + (size_t)jj*HD + qq*4);
          float u=u2_r[jj]; float s2j=u*sigm(u);
#pragma unroll
          for (int qq=0;qq<4;qq++){
            float pv[4]={P[qq].x,P[qq].y,P[qq].z,P[qq].w};
#pragma unroll
            for (int m=0;m<4;m++)
              nw2_1[jj*16+qq*4+m] = fmaf(et_, nw2_1[jj*16+qq*4+m],
                                         fmaf(cP_, pv[m], -th_*(s2j*g2v16[qq*4+m])));
          }
        }
        if (tid < 128){
          float g2vt = 0.015625f*(h2k[padb(tid)] - vSt[padb(tid)]);
          b2n1[tid] = fmaf(et_, b2n1[tid], fmaf(cP_, b2p1[tid], -th_*g2vt));
        }
      }
      if ((tid & 7) == 0){
#pragma unroll
        for (int jj=0;jj<4;jj++)
          b1n1[j1+jj] = fmaf(et_, b1n1[j1+jj], fmaf(cP_, b1p1[j1+jj], -th_*gu2_r[jj]));
      }
      // prefetch v_{t+1}
      const int tn2 = (t < SEQ-1) ? t+1 : SEQ-1;
#pragma unroll
      for (int ii=0;ii<4;ii++) v_r[ii] = vbuf[((size_t)b*SEQ + tn2)*HD + i0+ii];
      if (tid < 128) vS[par][padb(tid)] = vbuf[((size_t)b*SEQ + tn2)*HD + tid];
    }
    // ---------- the ONE poll ----------
    if (tid < 256){
      float s0 = ro + pollacc(par, seq, tid, pown);
      if (tid < 128) h1q[padb(o_)] = s0;
      else           h1k[par][padb(o_)] = s0;
    }
    __syncthreads();                               // S_C
    // ---------- layer-1 forward (local, n_t) ----------
    float u2q[4]={0,0,0,0}, u2k[4]={0,0,0,0};
#pragma unroll
    for (int r=0;r<4;r++){
      float4 hv = ld4(&h1q[padb(i1)+r*4]);
      float hvv[4]={hv.x,hv.y,hv.z,hv.w};
#pragma unroll
      for (int m=0;m<4;m++){
        float h_ = hvv[m];
#pragma unroll
        for (int jj=0;jj<4;jj++)
          u2q[jj] = fmaf(h_, nw1_1[(r*4+m)*4+jj], u2q[jj]);
      }
    }
    {
      const float* h1kn = h1k[par];
#pragma unroll
      for (int r=0;r<4;r++){
        float4 hv = ld4(&h1kn[padb(i1)+r*4]);
        float hvv[4]={hv.x,hv.y,hv.z,hv.w};
#pragma unroll
        for (int m=0;m<4;m++){
          float h_ = hvv[m];
#pragma unroll
          for (int jj=0;jj<4;jj++)
            u2k[jj] = fmaf(h_, nw1_1[(r*4+m)*4+jj], u2k[jj]);
        }
      }
    }
#pragma unroll
    for (int d=1; d<8; d<<=1){
#pragma unroll
      for (int jj=0;jj<4;jj++){
        u2q[jj] += __shfl_xor(u2q[jj], d, 64);
        u2k[jj] += __shfl_xor(u2k[jj], d, 64);
      }
    }
    float s2q[4], s2k[4];
#pragma unroll
    for (int jj=0;jj<4;jj++){
      float bb = b1n1[j1+jj];
      float a = u2q[jj] + bb, c = u2k[jj] + bb;
      u2_r[jj] = c;
      s2q[jj] = a*sigm(a);
      s2k[jj] = c*sigm(c);
    }
    // layer-1 out partials: q path then k path (caps register pressure)
    {
      float ho[16];
#pragma unroll
      for (int oo=0;oo<16;oo++) ho[oo]=0.f;
#pragma unroll
      for (int jj=0;jj<4;jj++){
        float s_ = s2q[jj];
#pragma unroll
        for (int oo=0;oo<16;oo++) ho[oo] = fmaf(s_, nw2_1[jj*16+oo], ho[oo]);
      }
#pragma unroll
      for (int d=8; d<64; d<<=1){
#pragma unroll
        for (int oo=0;oo<16;oo++) ho[oo] += __shfl_xor(ho[oo], d, 64);
      }
      if ((tid&56)==0){
#pragma unroll
        for (int r=0;r<4;r++){
          float4 s; s.x=ho[r*4]; s.y=ho[r*4+1]; s.z=ho[r*4+2]; s.w=ho[r*4+3];
          *reinterpret_cast<float4*>(&redbuf[w8][padb(i1)+r*4]) = s;
        }
      }
#pragma unroll
      for (int oo=0;oo<16;oo++) ho[oo]=0.f;
#pragma unroll
      for (int jj=0;jj<4;jj++){
        float s_ = s2k[jj];
#pragma unroll
        for (int oo=0;oo<16;oo++) ho[oo] = fmaf(s_, nw2_1[jj*16+oo], ho[oo]);
      }
#pragma unroll
      for (int d=8; d<64; d<<=1){
#pragma unroll
        for (int oo=0;oo<16;oo++) ho[oo] += __shfl_xor(ho[oo], d, 64);
      }
      if ((tid&56)==0){
#pragma unroll
        for (int r=0;r<4;r++){
          float4 s; s.x=ho[r*4]; s.y=ho[r*4+1]; s.z=ho[r*4+2]; s.w=ho[r*4+3];
          *reinterpret_cast<float4*>(&redbuf[w8][156+padb(i1)+r*4]) = s;
        }
      }
    }
    __syncthreads();                               // S_D
    if (tid < 256){
      float s = 0.f;
#pragma unroll
      for (int w_=0; w_<8; w_++) s += redbuf[w_][half*156 + padb(o_)];
      s += b2n1[o_];
      if (tid < 128){
        if (writeOut && o_ >= wg*32 && o_ < wg*32+32)
          out[((size_t)(b*SEQ + t))*HD + o_] = h1q[padb(o_)] + s;
      } else {
        h2k[padb(o_)] = h1k[par][padb(o_)] + s;
      }
    }
  };

  // ---- prologue: forward k_0 with n_{-1} = p0 + m0 ----
  {
#pragma unroll
    for (int ii=0;ii<4;ii++){
      kprev4[ii] = kbuf[((size_t)b*SEQ + 0)*HD + i0+ii];
      v_r[ii]    = vbuf[((size_t)b*SEQ + 0)*HD + i0+ii];
    }
    if (tid < 128) vS[0][padb(tid)] = vbuf[((size_t)b*SEQ + 0)*HD + tid];
    float ro0 = 0.f;
    if (tid >= 128 && tid < 256)
      ro0 = kbuf[((size_t)b*SEQ + 0)*HD + (tid-128)];
    __syncthreads();   // init (LDS p0/biases/vS) visible
    float ak0[4]={0,0,0,0};
#pragma unroll
    for (int ii=0;ii<4;ii++){
      float ki = kprev4[ii];
#pragma unroll
      for (int jj=0;jj<4;jj++) ak0[jj] = fmaf(ki, nw1_0[jj*4+ii], ak0[jj]);
    }
#pragma unroll
    for (int d=1; d<32; d<<=1){
#pragma unroll
      for (int jj=0;jj<4;jj++) ak0[jj] += __shfl_xor(ak0[jj], d, 64);
    }
    float uq0[4], uk0[4];
#pragma unroll
    for (int jj=0;jj<4;jj++){
      float bb = b1n0[j0+jj];
      uq0[jj] = bb;              // q-path dummy (discarded, finite)
      uk0[jj] = ak0[jj] + bb;
      u1_r[jj] = uk0[jj];
    }
    fwd(0, false, false, uq0, uk0, ro0);   // par=0, seq=1
  }

  float dPrev = 1.f;   // 1 - alpha_{-1}
  for (int t=0; t<SEQ; ++t){
    const int g  = t+1;
    const int tn = (t < SEQ-1) ? t+1 : SEQ-1;
    __syncthreads();                       // S_E: h2k/u2 state from prev fwd visible
    // ---- P1: loads (latency hidden under bwd compute) ----
    float qv4[4], kv4[4];
#pragma unroll
    for (int ii=0;ii<4;ii++){
      qv4[ii] = qbuf[((size_t)b*SEQ + t )*HD + i0+ii];
      kv4[ii] = kbuf[((size_t)b*SEQ + tn)*HD + i0+ii];
    }
    float ro = 0.f;
    if (tid < 128)      ro = qbuf[((size_t)b*SEQ + t )*HD + tid];
    else if (tid < 256) ro = kbuf[((size_t)b*SEQ + tn)*HD + (tid-128)];
    th_ = thb[b*SEQ+t];
    const float al = alb[b*SEQ+t];
    et_ = etb[b*SEQ+t];
    const float dcur = 1.f - al;
    cP_ = dcur - et_*dPrev;
    // ---- P2: g2v at layer-0 range ----
    float g2v_r[4];
    {
      float4 hh = ld4(&h2k[padb(i0)]);
      g2v_r[0]=0.015625f*(hh.x-v_r[0]); g2v_r[1]=0.015625f*(hh.y-v_r[1]);
      g2v_r[2]=0.015625f*(hh.z-v_r[2]); g2v_r[3]=0.015625f*(hh.w-v_r[3]);
    }
    // ---- P3: gu2 (weights n_{t-1}) — fully local now ----
    {
      const float* vSt = vS[t&1];
      float acc2[4]={0,0,0,0};
#pragma unroll
      for (int r=0;r<4;r++){
        float4 hv = ld4(&h2k[padb(i1)+r*4]);
        float4 vv = ld4(&vSt[padb(i1)+r*4]);
        float gv[4] = {0.015625f*(hv.x-vv.x), 0.015625f*(hv.y-vv.y),
                       0.015625f*(hv.z-vv.z), 0.015625f*(hv.w-vv.w)};
#pragma unroll
        for (int m=0;m<4;m++){
#pragma unroll
          for (int jj=0;jj<4;jj++)
            acc2[jj] = fmaf(gv[m], nw2_1[jj*16+r*4+m], acc2[jj]);
        }
      }
#pragma unroll
      for (int d=1; d<8; d<<=1){
#pragma unroll
        for (int jj=0;jj<4;jj++) acc2[jj] += __shfl_xor(acc2[jj], d, 64);
      }
#pragma unroll
      for (int jj=0;jj<4;jj++){
        float u = u2_r[jj]; float sg = sigm(u);
        gu2_r[jj] = acc2[jj]*sg*fmaf(u, 1.f-sg, 1.f);
      }
    }
    // ---- P4: gh1 partials over FULL ED (local; cross-wave via redA) ----
    {
      float a2[16];
#pragma unroll
      for (int ii=0;ii<16;ii++) a2[ii]=0.f;
#pragma unroll
      for (int jj=0;jj<4;jj++){
        float gj = gu2_r[jj];
#pragma unroll
        for (int ii=0;ii<16;ii++) a2[ii] = fmaf(gj, nw1_1[ii*4+jj], a2[ii]);
      }
#pragma unroll
      for (int d=8; d<64; d<<=1){
#pragma unroll
        for (int ii=0;ii<16;ii++) a2[ii] += __shfl_xor(a2[ii], d, 64);
      }
      if ((tid&56)==0){
#pragma unroll
        for (int r=0;r<4;r++){
          float4 s; s.x=a2[r*4]; s.y=a2[r*4+1]; s.z=a2[r*4+2]; s.w=a2[r*4+3];
          *reinterpret_cast<float4*>(&redA[w8][padb(i1)+r*4]) = s;
        }
      }
    }
    __syncthreads();                       // S_A
    // ---- P5: gh1 at own indices (per-thread 8-row sum; no extra barrier) ----
    float gh1_r[4];
    {
      float sx=g2v_r[0], sy=g2v_r[1], sz=g2v_r[2], sw=g2v_r[3];
#pragma unroll
      for (int w_=0; w_<8; w_++){
        float4 rr = ld4(&redA[w_][padb(i0)]);
        sx+=rr.x; sy+=rr.y; sz+=rr.z; sw+=rr.w;
      }
      gh1_r[0]=sx; gh1_r[1]=sy; gh1_r[2]=sz; gh1_r[3]=sw;
    }
    float gu1r[4];
    {
      float acc1[4]={0,0,0,0};
#pragma unroll
      for (int oo=0;oo<4;oo++){
        float go = gh1_r[oo];
#pragma unroll
        for (int jj=0;jj<4;jj++) acc1[jj] = fmaf(go, nw2_0[jj*4+oo], acc1[jj]);
      }
#pragma unroll
      for (int d=1; d<32; d<<=1){
#pragma unroll
        for (int jj=0;jj<4;jj++) acc1[jj] += __shfl_xor(acc1[jj], d, 64);
      }
#pragma unroll
      for (int jj=0;jj<4;jj++){
        float u = u1_r[jj]; float sg = sigm(u);
        gu1r[jj] = acc1[jj]*sg*fmaf(u, 1.f-sg, 1.f);
      }
    }
    // ---- P6: layer-0 n-updates (LDS p0) ----
    {
      float s1ko[4];
#pragma unroll
      for (int jj=0;jj<4;jj++){ float u=u1_r[jj]; s1ko[jj]=u*sigm(u); }
#pragma unroll
      for (int jj=0;jj<4;jj++){
#pragma unroll
        for (int ii=0;ii<4;ii++){
          int e = jj*4+ii;
          nw1_0[e] = fmaf(et_, nw1_0[e], fmaf(cP_, pw1L0[e][tid], -th_*(kprev4[ii]*gu1r[jj])));
          nw2_0[e] = fmaf(et_, nw2_0[e], fmaf(cP_, pw2L0[e][tid], -th_*(s1ko[jj]*gh1_r[ii])));
        }
      }
      if (iG==0){
#pragma unroll
        for (int jj=0;jj<4;jj++)
          b1n0[j0+jj] = fmaf(et_, b1n0[j0+jj], fmaf(cP_, b1p0[j0+jj], -th_*gu1r[jj]));
      }
      if (jG==0 && iG>=wg*8 && iG<wg*8+8){
#pragma unroll
        for (int ii=0;ii<4;ii++)
          b2n0[i0+ii-wg*32] = fmaf(et_, b2n0[i0+ii-wg*32],
                                   fmaf(cP_, b2p0[i0+ii-wg*32], -th_*gh1_r[ii]));
      }
    }
    // ---- P7: layer-0 dual u with n_t ----
    float uqf[4], ukf[4];
    {
      float aq[4]={0,0,0,0}, ak[4]={0,0,0,0};
#pragma unroll
      for (int ii=0;ii<4;ii++){
        float qi = qv4[ii], ki = kv4[ii];
#pragma unroll
        for (int jj=0;jj<4;jj++){
          float w = nw1_0[jj*4+ii];
          aq[jj] = fmaf(qi, w, aq[jj]);
          ak[jj] = fmaf(ki, w, ak[jj]);
        }
      }
#pragma unroll
      for (int d=1; d<32; d<<=1){
#pragma unroll
        for (int jj=0;jj<4;jj++){
          aq[jj] += __shfl_xor(aq[jj], d, 64);
          ak[jj] += __shfl_xor(ak[jj], d, 64);
        }
      }
#pragma unroll
      for (int jj=0;jj<4;jj++){
        float bb = b1n0[j0+jj];   // wave-local RAW (writer iG==0 same wave)
        uqf[jj] = aq[jj] + bb;
        ukf[jj] = ak[jj] + bb;
      }
    }
#pragma unroll
    for (int ii=0;ii<4;ii++) kprev4[ii] = kv4[ii];
#pragma unroll
    for (int jj=0;jj<4;jj++) u1_r[jj] = ukf[jj];
    dPrev = dcur;
    fwd(g, true, true, uqf, ukf, ro);
  }
}

extern "C" void kernel_launch(void* const* d_in, const int* in_sizes, int n_in,
                              void* d_out, int out_size, void* d_ws, size_t ws_size,
                              hipStream_t stream)
{
  (void)in_sizes; (void)n_in; (void)out_size; (void)ws_size;
  const float* x    = (const float*)d_in[0];
  const float* Wq   = (const float*)d_in[1];
  const float* Wk   = (const float*)d_in[2];
  const float* Wv   = (const float*)d_in[3];
  const float* w_lr = (const float*)d_in[4];
  const float* b_lr = (const float*)d_in[5];
  const float* w_fg = (const float*)d_in[6];
  const float* b_fg = (const float*)d_in[7];
  const float* w_mo = (const float*)d_in[8];
  const float* b_mo = (const float*)d_in[9];
  const float* w1_0 = (const float*)d_in[10];
  const float* b1_0 = (const float*)d_in[11];
  const float* w2_0 = (const float*)d_in[12];
  const float* b2_0 = (const float*)d_in[13];
  const float* m_w1_0 = (const float*)d_in[14];
  const float* m_b1_0 = (const float*)d_in[15];
  const float* m_w2_0 = (const float*)d_in[16];
  const float* m_b2_0 = (const float*)d_in[17];
  const float* w1_1 = (const float*)d_in[18];
  const float* b1_1 = (const float*)d_in[19];
  const float* w2_1 = (const float*)d_in[20];
  const float* b2_1 = (const float*)d_in[21];
  const float* m_w1_1 = (const float*)d_in[22];
  const float* m_b1_1 = (const float*)d_in[23];
  const float* m_w2_1 = (const float*)d_in[24];
  const float* m_b2_1 = (const float*)d_in[25];

  float* wsf = (float*)d_ws;
  unsigned long long* red = (unsigned long long*)d_ws;   // 64 KB of slots ([b][par][wg][256])
  float* qbuf = wsf + 32768;
  float* kbuf = qbuf + NB*SEQ*HD;
  float* vbuf = kbuf + NB*SEQ*HD;
  float* thb  = vbuf + NB*SEQ*HD;
  float* alb  = thb + NB*SEQ;
  float* etb  = alb + NB*SEQ;
  // ws re-poisoned to 0xAA each launch; 0xAAAAAAAA is never a valid seq tag.

  qkv_kernel<<<dim3(NB*SEQ), dim3(HD), 0, stream>>>(
      x, Wq, Wk, Wv, w_lr, b_lr, w_fg, b_fg, w_mo, b_mo,
      qbuf, kbuf, vbuf, thb, alb, etb);

  scan_kernel<<<dim3(NB*NWG), dim3(512), 0, stream>>>(
      w1_0, b1_0, w2_0, b2_0, m_w1_0, m_b1_0, m_w2_0, m_b2_0,
      w1_1, b1_1, w2_1, b2_1, m_w1_1, m_b1_1, m_w2_1, m_b2_1,
      qbuf, kbuf, vbuf, thb, alb, etb,
      red, (float*)d_out);
}

// Round 3
// 2736.226 us; speedup vs baseline: 1.9026x; 1.9001x over previous
//
#include <hip/hip_runtime.h>

// NeuralMemory scan: B=4, S=256, H=128, EXP=2, DEPTH=2.
// Round 13: R10 base (verified 2392us) + q-path deferral into exposed poll
// windows. R11/R12 post-mortem: layer-1 replication can't get >128 VGPRs
// (two attempts, identical counters) and is ~net-neutral even if it could
// (saved polls eaten by 4x-redundant L1 VALU + 256KB/step L2 p0 streaming
// on the in-order vmcnt path). Abandoned.
// This round: the q-path is NOT on the serial chain (out[t] is a sink; only
// the k-path feeds step t+1). R10 interleaved q+k, doubling chain VALU while
// poll-1/poll-2 windows sat empty. Now:
//   - k-only on the chain (L0-u, L0-out, L1-u, L1-out all halved)
//   - q L0 fwd computed inside poll-1k's window (all threads; waves 2-3
//     spin 1k, waves 0-1 spin 2q concurrently)
//   - q L1 fwd computed inside the NEXT step's B-shadow, BEFORE the L1
//     update there (regs hold exactly n_t, the version q(t) needs;
//     b2n1 snapshotted pre-update)
//   - h1q poll (1q) inside poll-2k's window (waves 0-1 vs 2-3 overlapped)
//   - h2q poll (2q) + out-write trail into next step's poll-1k window;
//     epilogue flushes out[SEQ-1].
// Slot map (3 types x 4wg x 256 slots, unchanged 98304B): type0 idx<128 = B
// (tag t+1); type1 idx<128 = 1q / idx>=128 = 1k (tag t+2); type2 idx<128 =
// 2q (tag t+1, q of step t-1) / idx>=128 = 2k (tag t+2). Overwrite safety:
// same publish-before-poll chain argument as R10 (each slot's next write is
// gated through partners' completed reads via the B-poll).

constexpr int HD  = 128;   // H
constexpr int SEQ = 256;   // S
constexpr int NB  = 4;     // B
constexpr int ED  = 256;   // H*EXP
constexpr int CW  = 64;    // hidden units per WG per layer (ED/NWG)
constexpr int NWG = 4;     // workgroups per batch

__device__ __forceinline__ float sigm(float x){ return 1.0f/(1.0f+__expf(-x)); }

// ---------------- kernel 1: q/k/v + gate scalars (unchanged) ----------------
__global__ __launch_bounds__(128) void qkv_kernel(
    const float* __restrict__ x,
    const float* __restrict__ Wq, const float* __restrict__ Wk, const float* __restrict__ Wv,
    const float* __restrict__ w_lr, const float* __restrict__ b_lr,
    const float* __restrict__ w_fg, const float* __restrict__ b_fg,
    const float* __restrict__ w_mo, const float* __restrict__ b_mo,
    float* __restrict__ qb, float* __restrict__ kb, float* __restrict__ vb,
    float* __restrict__ thb, float* __restrict__ alb, float* __restrict__ etb)
{
  const int bs = blockIdx.x;
  const int o  = threadIdx.x;
  __shared__ float xl[HD];
  __shared__ float rb[HD];
  xl[o] = x[(size_t)bs*HD + o];
  __syncthreads();

  float aq=0.f, ak=0.f, av=0.f;
  #pragma unroll 8
  for (int i=0;i<HD;i++){
    float xi = xl[i];
    aq = fmaf(xi, Wq[i*HD+o], aq);
    ak = fmaf(xi, Wk[i*HD+o], ak);
    av = fmaf(xi, Wv[i*HD+o], av);
  }
  float sq_ = aq*sigm(aq);
  float sk_ = ak*sigm(ak);
  float sv_ = av*sigm(av);

  auto bsum = [&](float v)->float {
    rb[o] = v; __syncthreads();
    for (int st=64; st>0; st>>=1){
      if (o < st) rb[o] += rb[o+st];
      __syncthreads();
    }
    float r = rb[0];
    __syncthreads();
    return r;
  };

  float nq = bsum(sq_*sq_);
  float nk = bsum(sk_*sk_);
  float dl = bsum(xl[o]*w_lr[o]);
  float df = bsum(xl[o]*w_fg[o]);
  float dm = bsum(xl[o]*w_mo[o]);

  qb[(size_t)bs*HD+o] = sq_ / fmaxf(sqrtf(nq), 1e-12f);
  kb[(size_t)bs*HD+o] = sk_ / fmaxf(sqrtf(nk), 1e-12f);
  vb[(size_t)bs*HD+o] = sv_;
  if (o==0){
    thb[bs] = sigm(dl + b_lr[0]) * 0.01f;
    alb[bs] = sigm(df + b_fg[0]);
    etb[bs] = sigm(dm + b_mo[0]);
  }
}

// ---------------- kernel 2: the sequential scan ----------------
__global__ __launch_bounds__(512, 1) void scan_kernel(
    const float* __restrict__ w1_0g, const float* __restrict__ b1_0g,
    const float* __restrict__ w2_0g, const float* __restrict__ b2_0g,
    const float* __restrict__ mw1_0g, const float* __restrict__ mb1_0g,
    const float* __restrict__ mw2_0g, const float* __restrict__ mb2_0g,
    const float* __restrict__ w1_1g, const float* __restrict__ b1_1g,
    const float* __restrict__ w2_1g, const float* __restrict__ b2_1g,
    const float* __restrict__ mw1_1g, const float* __restrict__ mb1_1g,
    const float* __restrict__ mw2_1g, const float* __restrict__ mb2_1g,
    const float* __restrict__ qbuf, const float* __restrict__ kbuf, const float* __restrict__ vbuf,
    const float* __restrict__ thb, const float* __restrict__ alb, const float* __restrict__ etb,
    unsigned long long* __restrict__ red, float* __restrict__ out)
{
  const int bid = blockIdx.x;
  const int b   = bid & 3;
  const int wg  = bid >> 2;
  const int tid = threadIdx.x;
  const int iG  = tid & 31;
  const int jG  = tid >> 5;
  const int i0  = iG*4;
  const int j0  = jG*4;
  const int c0  = wg*CW;

  __shared__ float pw1L[2][16][512];   // 64 KB p0 (w1)
  __shared__ float pw2L[2][16][512];   // 64 KB p0 (w2)
  __shared__ float h1k[HD], h1q[HD], h2k[HD], gh1[HD];  // h1q = q-stash (cross-step)
  __shared__ float redbuf[8][256];     // q-half cols [0,128), k-half [128,256)
  __shared__ float b1p[2][CW], b1n[2][CW], b2p[2][32], b2n[2][32];

  float nw1[2][16], nw2[2][16];
  {
    const float* w1s[2]  = {w1_0g,  w1_1g};
    const float* mw1s[2] = {mw1_0g, mw1_1g};
    const float* w2s[2]  = {w2_0g,  w2_1g};
    const float* mw2s[2] = {mw2_0g, mw2_1g};
    #pragma unroll
    for (int l=0;l<2;l++){
      #pragma unroll
      for (int jj=0;jj<4;jj++){
        #pragma unroll
        for (int ii=0;ii<4;ii++){
          int gi1 = (i0+ii)*ED + (c0+j0+jj);
          float p1 = w1s[l][gi1];
          pw1L[l][jj*4+ii][tid] = p1;
          nw1[l][jj*4+ii] = p1 + mw1s[l][gi1];   // n_{-1} = p0 + m0
          int gi2 = (c0+j0+jj)*HD + (i0+ii);
          float p2 = w2s[l][gi2];
          pw2L[l][jj*4+ii][tid] = p2;
          nw2[l][jj*4+ii] = p2 + mw2s[l][gi2];
        }
      }
    }
  }
  if (tid < CW){
    float p0a = b1_0g[c0+tid], p1a = b1_1g[c0+tid];
    b1p[0][tid] = p0a; b1n[0][tid] = p0a + mb1_0g[c0+tid];
    b1p[1][tid] = p1a; b1n[1][tid] = p1a + mb1_1g[c0+tid];
  } else if (tid < CW+32){
    int oo = tid - CW;
    float p0a = b2_0g[wg*32+oo], p1a = b2_1g[wg*32+oo];
    b2p[0][oo] = p0a; b2n[0][oo] = p0a + mb2_0g[wg*32+oo];
    b2p[1][oo] = p1a; b2n[1][oo] = p1a + mb2_1g[wg*32+oo];
  }

  auto pubstore = [&](int type, unsigned seq, int idx, float val){
    unsigned long long* p = red + (((b*3+type)*NWG + wg)*256 + idx);
    unsigned long long pk = ((unsigned long long)seq << 32) |
                            (unsigned long long)__float_as_uint(val);
    __hip_atomic_store(p, pk, __ATOMIC_RELAXED, __HIP_MEMORY_SCOPE_AGENT);
  };
  auto preload = [&](int type, int idx,
                     unsigned long long& vA, unsigned long long& vB, unsigned long long& vC){
    unsigned long long* base = red + ((b*3+type)*NWG)*256;
    vA = __hip_atomic_load(base+((wg+1)&3)*256+idx, __ATOMIC_RELAXED, __HIP_MEMORY_SCOPE_AGENT);
    vB = __hip_atomic_load(base+((wg+2)&3)*256+idx, __ATOMIC_RELAXED, __HIP_MEMORY_SCOPE_AGENT);
    vC = __hip_atomic_load(base+((wg+3)&3)*256+idx, __ATOMIC_RELAXED, __HIP_MEMORY_SCOPE_AGENT);
  };
  auto pollfin = [&](int type, unsigned seq, int idx, float own,
                     unsigned long long vA, unsigned long long vB, unsigned long long vC)->float{
    unsigned long long* base = red + ((b*3+type)*NWG)*256;
    const int wA=((wg+1)&3)*256+idx, wB=((wg+2)&3)*256+idx, wC=((wg+3)&3)*256+idx;
    float s = own; unsigned got = 0;
    while (got != 7u){
      if (!(got&1u)){
        if ((unsigned)(vA>>32)==seq){ s += __uint_as_float((unsigned)vA); got|=1u; }
        else vA = __hip_atomic_load(base+wA, __ATOMIC_RELAXED, __HIP_MEMORY_SCOPE_AGENT);
      }
      if (!(got&2u)){
        if ((unsigned)(vB>>32)==seq){ s += __uint_as_float((unsigned)vB); got|=2u; }
        else vB = __hip_atomic_load(base+wB, __ATOMIC_RELAXED, __HIP_MEMORY_SCOPE_AGENT);
      }
      if (!(got&4u)){
        if ((unsigned)(vC>>32)==seq){ s += __uint_as_float((unsigned)vC); got|=4u; }
        else vC = __hip_atomic_load(base+wC, __ATOMIC_RELAXED, __HIP_MEMORY_SCOPE_AGENT);
      }
    }
    return s;
  };
  auto pollacc = [&](int type, unsigned seq, int idx, float own)->float{
    unsigned long long vA, vB, vC;
    preload(type, idx, vA, vB, vC);
    return pollfin(type, seq, idx, own, vA, vB, vC);
  };

  // loop-carried per-thread state
  float u1_r[4];       // k-path L0 preacts (grad key k_t)
  float u2_r[4];       // k-path L1 preacts
  float s2_r[4];       // k-path L1 silu
  float h1k_r[4];      // h1k at i0 (for L1-w1 update)
  float kprev4[4];     // k_t at i0
  float v_r[4];        // v_t at i0
  float vc_r = 0.f;    // v_t at tid (tid<128)
  float th_=0.f, et_=0.f, cP_=0.f;
  float gu2_r[4];

  // ---- prologue: forward k_0 with n_{-1} = p0 + m0 (m0=0), k-path only ----
  {
    #pragma unroll
    for (int ii=0;ii<4;ii++){
      kprev4[ii] = kbuf[((size_t)b*SEQ + 0)*HD + i0+ii];
      v_r[ii]    = vbuf[((size_t)b*SEQ + 0)*HD + i0+ii];
    }
    if (tid < HD) vc_r = vbuf[((size_t)b*SEQ + 0)*HD + tid];
    float rok0 = 0.f;
    if (tid >= 128 && tid < 256)
      rok0 = kbuf[((size_t)b*SEQ + 0)*HD + (tid-128)];
    __syncthreads();   // init (LDS p0/biases) visible
    float ak0[4]={0,0,0,0};
    #pragma unroll
    for (int ii=0;ii<4;ii++){
      float ki = kprev4[ii];
      #pragma unroll
      for (int jj=0;jj<4;jj++) ak0[jj] = fmaf(ki, nw1[0][jj*4+ii], ak0[jj]);
    }
    #pragma unroll
    for (int d=1; d<32; d<<=1){
      #pragma unroll
      for (int jj=0;jj<4;jj++) ak0[jj] += __shfl_xor(ak0[jj], d, 64);
    }
    float s1k[4];
    #pragma unroll
    for (int jj=0;jj<4;jj++){
      float u = ak0[jj] + b1n[0][j0+jj];
      u1_r[jj] = u; s1k[jj] = u*sigm(u);
    }
    float ok[4]={0,0,0,0};
    #pragma unroll
    for (int jj=0;jj<4;jj++){
      #pragma unroll
      for (int oo=0;oo<4;oo++) ok[oo] = fmaf(s1k[jj], nw2[0][jj*4+oo], ok[oo]);
    }
    #pragma unroll
    for (int oo=0;oo<4;oo++) ok[oo] += __shfl_xor(ok[oo], 32, 64);
    if (!(tid & 32)){
      const int wv = tid >> 6;
      #pragma unroll
      for (int oo=0;oo<4;oo++) redbuf[wv][128+i0+oo] = ok[oo];
    }
    __syncthreads();                       // S4
    if (tid >= 128 && tid < 256){
      float s = 0.f;
      #pragma unroll
      for (int w_=0; w_<8; w_++) s += redbuf[w_][tid];
      int o_ = tid - 128;
      if (o_ >= wg*32 && o_ < wg*32+32) s += b2n[0][o_-wg*32];
      pubstore(1, 1u, tid, s);
      float s0 = rok0 + pollacc(1, 1u, tid, s);
      h1k[o_] = s0;
    }
    __syncthreads();                       // S5
    float ak2[4]={0,0,0,0};
    #pragma unroll
    for (int ii=0;ii<4;ii++){
      float ki = h1k[i0+ii];
      h1k_r[ii] = ki;
      #pragma unroll
      for (int jj=0;jj<4;jj++) ak2[jj] = fmaf(ki, nw1[1][jj*4+ii], ak2[jj]);
    }
    #pragma unroll
    for (int d=1; d<32; d<<=1){
      #pragma unroll
      for (int jj=0;jj<4;jj++) ak2[jj] += __shfl_xor(ak2[jj], d, 64);
    }
    float s2k[4];
    #pragma unroll
    for (int jj=0;jj<4;jj++){
      float u = ak2[jj] + b1n[1][j0+jj];
      u2_r[jj] = u; s2k[jj] = u*sigm(u); s2_r[jj] = s2k[jj];
    }
    float ok2[4]={0,0,0,0};
    #pragma unroll
    for (int jj=0;jj<4;jj++){
      #pragma unroll
      for (int oo=0;oo<4;oo++) ok2[oo] = fmaf(s2k[jj], nw2[1][jj*4+oo], ok2[oo]);
    }
    #pragma unroll
    for (int oo=0;oo<4;oo++) ok2[oo] += __shfl_xor(ok2[oo], 32, 64);
    if (!(tid & 32)){
      const int wv = tid >> 6;
      #pragma unroll
      for (int oo=0;oo<4;oo++) redbuf[wv][128+i0+oo] = ok2[oo];
    }
    __syncthreads();                       // S6
    if (tid >= 128 && tid < 256){
      float s = 0.f;
      #pragma unroll
      for (int w_=0; w_<8; w_++) s += redbuf[w_][tid];
      int o_ = tid - 128;
      if (o_ >= wg*32 && o_ < wg*32+32) s += b2n[1][o_-wg*32];
      pubstore(2, 1u, tid, s);
      float h2 = pollacc(2, 1u, tid, s);
      h2k[o_] = h1k[o_] + h2;
    }
  }

  float dPrev = 1.f;   // 1 - alpha_{-1}
  for (int t=0; t<SEQ; ++t){
    const int tn = (t < SEQ-1) ? t+1 : SEQ-1;
    __syncthreads();                       // S_E: h2k + h1q-stash from prev step visible
    // ---- P1: loads (hidden under bwd) ----
    float qv4[4], kv4[4];
    #pragma unroll
    for (int ii=0;ii<4;ii++){
      qv4[ii] = qbuf[((size_t)b*SEQ + t )*HD + i0+ii];
      kv4[ii] = kbuf[((size_t)b*SEQ + tn)*HD + i0+ii];
    }
    float ro = 0.f;   // tid<128: q_t residual ; tid in [128,256): k_{t+1} residual
    if (tid < 128)      ro = qbuf[((size_t)b*SEQ + t )*HD + tid];
    else if (tid < 256) ro = kbuf[((size_t)b*SEQ + tn)*HD + (tid-128)];
    th_ = thb[b*SEQ+t];
    const float al = alb[b*SEQ+t];
    et_ = etb[b*SEQ+t];
    const float dcur = 1.f - al;
    cP_ = dcur - et_*dPrev;
    // ---- P2: g2v at i0 ----
    float g2v_r[4];
    #pragma unroll
    for (int ii=0;ii<4;ii++) g2v_r[ii] = 0.015625f*(h2k[i0+ii] - v_r[ii]);
    // ---- P3: gu2 (weights n_{t-1}) ----
    {
      float acc[4]={0,0,0,0};
      #pragma unroll
      for (int oo=0;oo<4;oo++){
        float go = g2v_r[oo];
        #pragma unroll
        for (int jj=0;jj<4;jj++) acc[jj] = fmaf(go, nw2[1][jj*4+oo], acc[jj]);
      }
      #pragma unroll
      for (int d=1; d<32; d<<=1){
        #pragma unroll
        for (int jj=0;jj<4;jj++) acc[jj] += __shfl_xor(acc[jj], d, 64);
      }
      #pragma unroll
      for (int jj=0;jj<4;jj++){
        float u = u2_r[jj]; float sg = sigm(u);
        gu2_r[jj] = acc[jj]*sg*fmaf(u, 1.f-sg, 1.f);
      }
    }
    // ---- P4: gh1 partials -> redbuf K-half ----
    {
      float a2[4]={0,0,0,0};
      #pragma unroll
      for (int jj=0;jj<4;jj++){
        float gj = gu2_r[jj];
        #pragma unroll
        for (int ii=0;ii<4;ii++) a2[ii] = fmaf(gj, nw1[1][jj*4+ii], a2[ii]);
      }
      #pragma unroll
      for (int ii=0;ii<4;ii++) a2[ii] += __shfl_xor(a2[ii], 32, 64);
      if (!(tid & 32)){
        const int wv = tid >> 6;
        #pragma unroll
        for (int ii=0;ii<4;ii++) redbuf[wv][128+i0+ii] = a2[ii];
      }
    }
    __syncthreads();                       // S2
    const unsigned seqB = (unsigned)(t+1);
    float pB = 0.f, g2vc = 0.f;
    if (tid < 128){
      #pragma unroll
      for (int w_=0; w_<8; w_++) pB += redbuf[w_][128+tid];
      pubstore(0, seqB, tid, pB);          // publish ASAP
      g2vc = 0.015625f*(h2k[tid] - vc_r);
    }
    // ---------- B shadow: L1-q fwd for q(t-1) (weights n_{t-1}) + L1 updates + prefetch ----------
    float b2q_keep = 0.f;
    if (t > 0){
      float aq2[4]={0,0,0,0};
      #pragma unroll
      for (int ii=0;ii<4;ii++){
        float qi = h1q[i0+ii];               // stash = h1q(t-1)
        #pragma unroll
        for (int jj=0;jj<4;jj++) aq2[jj] = fmaf(qi, nw1[1][jj*4+ii], aq2[jj]);
      }
      #pragma unroll
      for (int d=1; d<32; d<<=1){
        #pragma unroll
        for (int jj=0;jj<4;jj++) aq2[jj] += __shfl_xor(aq2[jj], d, 64);
      }
      float s2q[4];
      #pragma unroll
      for (int jj=0;jj<4;jj++){
        float u = aq2[jj] + b1n[1][j0+jj];   // pre-update = n_{t-1}
        s2q[jj] = u*sigm(u);
      }
      float oq[4]={0,0,0,0};
      #pragma unroll
      for (int jj=0;jj<4;jj++){
        #pragma unroll
        for (int oo=0;oo<4;oo++) oq[oo] = fmaf(s2q[jj], nw2[1][jj*4+oo], oq[oo]);
      }
      #pragma unroll
      for (int oo=0;oo<4;oo++) oq[oo] += __shfl_xor(oq[oo], 32, 64);
      if (!(tid & 32)){
        const int wv = tid >> 6;
        #pragma unroll
        for (int oo=0;oo<4;oo++) redbuf[wv][i0+oo] = oq[oo];   // Q-half
      }
      if (tid < 128 && tid >= wg*32 && tid < wg*32+32)
        b2q_keep = b2n[1][tid-wg*32];        // snapshot n_{t-1} bias
    }
    // L1 n-updates (produce n_t)
    #pragma unroll
    for (int jj=0;jj<4;jj++){
      float g2j = gu2_r[jj], s2j = s2_r[jj];
      #pragma unroll
      for (int ii=0;ii<4;ii++){
        int e = jj*4+ii;
        nw1[1][e] = fmaf(et_, nw1[1][e],
                         fmaf(cP_, pw1L[1][e][tid], -th_*(h1k_r[ii]*g2j)));
        nw2[1][e] = fmaf(et_, nw2[1][e],
                         fmaf(cP_, pw2L[1][e][tid], -th_*(s2j*g2v_r[ii])));
      }
    }
    if (iG==0){
      #pragma unroll
      for (int jj=0;jj<4;jj++)
        b1n[1][j0+jj] = fmaf(et_, b1n[1][j0+jj],
                             fmaf(cP_, b1p[1][j0+jj], -th_*gu2_r[jj]));
    }
    if (jG==0 && iG>=wg*8 && iG<wg*8+8){
      #pragma unroll
      for (int ii=0;ii<4;ii++)
        b2n[1][i0+ii-wg*32] = fmaf(et_, b2n[1][i0+ii-wg*32],
                                   fmaf(cP_, b2p[1][i0+ii-wg*32], -th_*g2v_r[ii]));
    }
    // prefetch v_{t+1}
    #pragma unroll
    for (int ii=0;ii<4;ii++) v_r[ii] = vbuf[((size_t)b*SEQ + tn)*HD + i0+ii];
    if (tid < HD) vc_r = vbuf[((size_t)b*SEQ + tn)*HD + tid];
    // ---- poll B ----
    if (tid < 128)
      gh1[tid] = g2vc + pollacc(0, seqB, tid, pB);
    __syncthreads();                       // S3
    // ---- post-S3: publish 2q (q(t-1) L1 partials) ASAP ----
    float own2q = 0.f;
    if (t > 0 && tid < 128){
      float s = 0.f;
      #pragma unroll
      for (int w_=0; w_<8; w_++) s += redbuf[w_][tid];   // Q-half from B-shadow
      if (tid >= wg*32 && tid < wg*32+32) s += b2q_keep;
      own2q = s;
      pubstore(2, (unsigned)(t+1), tid, s);
    }
    // ---- gu1 ----
    float gh1_r[4];
    #pragma unroll
    for (int ii=0;ii<4;ii++) gh1_r[ii] = gh1[i0+ii];
    float gu1r[4];
    {
      float acc1[4]={0,0,0,0};
      #pragma unroll
      for (int oo=0;oo<4;oo++){
        float go = gh1_r[oo];
        #pragma unroll
        for (int jj=0;jj<4;jj++) acc1[jj] = fmaf(go, nw2[0][jj*4+oo], acc1[jj]);
      }
      #pragma unroll
      for (int d=1; d<32; d<<=1){
        #pragma unroll
        for (int jj=0;jj<4;jj++) acc1[jj] += __shfl_xor(acc1[jj], d, 64);
      }
      #pragma unroll
      for (int jj=0;jj<4;jj++){
        float u = u1_r[jj]; float sg = sigm(u);
        gu1r[jj] = acc1[jj]*sg*fmaf(u, 1.f-sg, 1.f);
      }
    }
    // ---- L0 n-updates (produce n_t) ----
    {
      float s1ko[4];
      #pragma unroll
      for (int jj=0;jj<4;jj++){ float u=u1_r[jj]; s1ko[jj]=u*sigm(u); }
      #pragma unroll
      for (int jj=0;jj<4;jj++){
        #pragma unroll
        for (int ii=0;ii<4;ii++){
          int e = jj*4+ii;
          nw1[0][e] = fmaf(et_, nw1[0][e], fmaf(cP_, pw1L[0][e][tid], -th_*(kprev4[ii]*gu1r[jj])));
          nw2[0][e] = fmaf(et_, nw2[0][e], fmaf(cP_, pw2L[0][e][tid], -th_*(s1ko[jj]*gh1_r[ii])));
        }
      }
      if (iG==0){
        #pragma unroll
        for (int jj=0;jj<4;jj++)
          b1n[0][j0+jj] = fmaf(et_, b1n[0][j0+jj], fmaf(cP_, b1p[0][j0+jj], -th_*gu1r[jj]));
      }
      if (jG==0 && iG>=wg*8 && iG<wg*8+8){
        #pragma unroll
        for (int ii=0;ii<4;ii++)
          b2n[0][i0+ii-wg*32] = fmaf(et_, b2n[0][i0+ii-wg*32],
                                     fmaf(cP_, b2p[0][i0+ii-wg*32], -th_*gh1_r[ii]));
      }
    }
    // ---- L0-k fwd (n_t), k-only ----
    {
      float ak[4]={0,0,0,0};
      #pragma unroll
      for (int ii=0;ii<4;ii++){
        float ki = kv4[ii];
        #pragma unroll
        for (int jj=0;jj<4;jj++) ak[jj] = fmaf(ki, nw1[0][jj*4+ii], ak[jj]);
      }
      #pragma unroll
      for (int d=1; d<32; d<<=1){
        #pragma unroll
        for (int jj=0;jj<4;jj++) ak[jj] += __shfl_xor(ak[jj], d, 64);
      }
      float s1k[4];
      #pragma unroll
      for (int jj=0;jj<4;jj++){
        float u = ak[jj] + b1n[0][j0+jj];   // wave-local RAW (writer iG==0 same wave)
        u1_r[jj] = u; s1k[jj] = u*sigm(u);
      }
      float ok[4]={0,0,0,0};
      #pragma unroll
      for (int jj=0;jj<4;jj++){
        #pragma unroll
        for (int oo=0;oo<4;oo++) ok[oo] = fmaf(s1k[jj], nw2[0][jj*4+oo], ok[oo]);
      }
      #pragma unroll
      for (int oo=0;oo<4;oo++) ok[oo] += __shfl_xor(ok[oo], 32, 64);
      if (!(tid & 32)){
        const int wv = tid >> 6;
        #pragma unroll
        for (int oo=0;oo<4;oo++) redbuf[wv][128+i0+oo] = ok[oo];
      }
    }
    #pragma unroll
    for (int ii=0;ii<4;ii++) kprev4[ii] = kv4[ii];
    dPrev = dcur;
    __syncthreads();                       // S4
    // ---- S4 window: pub1k + preloads, then q L0 fwd (all), then spins ----
    unsigned long long kA=0,kB=0,kC=0, qA2=0,qB2=0,qC2=0;
    float own1k = 0.f;
    if (tid >= 128 && tid < 256){
      float s = 0.f;
      #pragma unroll
      for (int w_=0; w_<8; w_++) s += redbuf[w_][tid];
      int o_ = tid - 128;
      if (o_ >= wg*32 && o_ < wg*32+32) s += b2n[0][o_-wg*32];
      own1k = s;
      pubstore(1, (unsigned)(t+2), tid, s);
      preload(1, tid, kA, kB, kC);
    } else if (tid < 128 && t > 0){
      preload(2, tid, qA2, qB2, qC2);
    }
    // q(t) L0 fwd (n_t) — fills the poll window
    {
      float aq[4]={0,0,0,0};
      #pragma unroll
      for (int ii=0;ii<4;ii++){
        float qi = qv4[ii];
        #pragma unroll
        for (int jj=0;jj<4;jj++) aq[jj] = fmaf(qi, nw1[0][jj*4+ii], aq[jj]);
      }
      #pragma unroll
      for (int d=1; d<32; d<<=1){
        #pragma unroll
        for (int jj=0;jj<4;jj++) aq[jj] += __shfl_xor(aq[jj], d, 64);
      }
      float s1q[4];
      #pragma unroll
      for (int jj=0;jj<4;jj++){
        float u = aq[jj] + b1n[0][j0+jj];
        s1q[jj] = u*sigm(u);
      }
      float oq[4]={0,0,0,0};
      #pragma unroll
      for (int jj=0;jj<4;jj++){
        #pragma unroll
        for (int oo=0;oo<4;oo++) oq[oo] = fmaf(s1q[jj], nw2[0][jj*4+oo], oq[oo]);
      }
      #pragma unroll
      for (int oo=0;oo<4;oo++) oq[oo] += __shfl_xor(oq[oo], 32, 64);
      if (!(tid & 32)){
        const int wv = tid >> 6;
        #pragma unroll
        for (int oo=0;oo<4;oo++) redbuf[wv][i0+oo] = oq[oo];   // Q-half
      }
    }
    // spins (disjoint wave roles, concurrent)
    if (tid >= 128 && tid < 256){
      float s0 = ro + pollfin(1, (unsigned)(t+2), tid, own1k, kA, kB, kC);
      h1k[tid-128] = s0;
    } else if (tid < 128 && t > 0){
      float h2q = pollfin(2, (unsigned)(t+1), tid, own2q, qA2, qB2, qC2);
      out[((size_t)(b*SEQ + (t-1)))*HD + tid] = h1q[tid] + h2q;
    }
    __syncthreads();                       // S5
    // ---- L1-k u (n_t; b1n[1] updated in B-shadow) ----
    {
      float ak2[4]={0,0,0,0};
      #pragma unroll
      for (int ii=0;ii<4;ii++){
        float ki = h1k[i0+ii];
        h1k_r[ii] = ki;
        #pragma unroll
        for (int jj=0;jj<4;jj++) ak2[jj] = fmaf(ki, nw1[1][jj*4+ii], ak2[jj]);
      }
      #pragma unroll
      for (int d=1; d<32; d<<=1){
        #pragma unroll
        for (int jj=0;jj<4;jj++) ak2[jj] += __shfl_xor(ak2[jj], d, 64);
      }
      #pragma unroll
      for (int jj=0;jj<4;jj++){
        float u = ak2[jj] + b1n[1][j0+jj];
        u2_r[jj] = u; s2_r[jj] = u*sigm(u);
      }
    }
    // pub1q (q L0 partials committed by S5)
    float own1q = 0.f; unsigned long long qA=0,qB=0,qC=0;
    if (tid < 128){
      float s = 0.f;
      #pragma unroll
      for (int w_=0; w_<8; w_++) s += redbuf[w_][tid];
      if (tid >= wg*32 && tid < wg*32+32) s += b2n[0][tid-wg*32];
      own1q = s;
      pubstore(1, (unsigned)(t+2), tid, s);
      preload(1, tid, qA, qB, qC);
    }
    // ---- L1-k out partials ----
    {
      float ok2[4]={0,0,0,0};
      #pragma unroll
      for (int jj=0;jj<4;jj++){
        float s_ = s2_r[jj];
        #pragma unroll
        for (int oo=0;oo<4;oo++) ok2[oo] = fmaf(s_, nw2[1][jj*4+oo], ok2[oo]);
      }
      #pragma unroll
      for (int oo=0;oo<4;oo++) ok2[oo] += __shfl_xor(ok2[oo], 32, 64);
      if (!(tid & 32)){
        const int wv = tid >> 6;
        #pragma unroll
        for (int oo=0;oo<4;oo++) redbuf[wv][128+i0+oo] = ok2[oo];
      }
    }
    __syncthreads();                       // S6
    // ---- S6 window: pub2k+poll2k (waves 2-3) || poll1q -> h1q stash (waves 0-1) ----
    if (tid >= 128 && tid < 256){
      float s = 0.f;
      #pragma unroll
      for (int w_=0; w_<8; w_++) s += redbuf[w_][tid];
      int o_ = tid - 128;
      if (o_ >= wg*32 && o_ < wg*32+32) s += b2n[1][o_-wg*32];
      pubstore(2, (unsigned)(t+2), tid, s);
      float h2 = pollacc(2, (unsigned)(t+2), tid, s);
      h2k[o_] = h1k[o_] + h2;
    } else if (tid < 128){
      float h1 = ro + pollfin(1, (unsigned)(t+2), tid, own1q, qA, qB, qC);
      h1q[tid] = h1;                       // stash for next step's B-shadow
    }
  }
  // ---- epilogue: q(SEQ-1) L1 fwd (weights = n_{SEQ-1}, current) + out ----
  __syncthreads();
  {
    float aq2[4]={0,0,0,0};
    #pragma unroll
    for (int ii=0;ii<4;ii++){
      float qi = h1q[i0+ii];
      #pragma unroll
      for (int jj=0;jj<4;jj++) aq2[jj] = fmaf(qi, nw1[1][jj*4+ii], aq2[jj]);
    }
    #pragma unroll
    for (int d=1; d<32; d<<=1){
      #pragma unroll
      for (int jj=0;jj<4;jj++) aq2[jj] += __shfl_xor(aq2[jj], d, 64);
    }
    float s2q[4];
    #pragma unroll
    for (int jj=0;jj<4;jj++){
      float u = aq2[jj] + b1n[1][j0+jj];
      s2q[jj] = u*sigm(u);
    }
    float oq[4]={0,0,0,0};
    #pragma unroll
    for (int jj=0;jj<4;jj++){
      #pragma unroll
      for (int oo=0;oo<4;oo++) oq[oo] = fmaf(s2q[jj], nw2[1][jj*4+oo], oq[oo]);
    }
    #pragma unroll
    for (int oo=0;oo<4;oo++) oq[oo] += __shfl_xor(oq[oo], 32, 64);
    if (!(tid & 32)){
      const int wv = tid >> 6;
      #pragma unroll
      for (int oo=0;oo<4;oo++) redbuf[wv][i0+oo] = oq[oo];
    }
  }
  __syncthreads();
  if (tid < 128){
    float s = 0.f;
    #pragma unroll
    for (int w_=0; w_<8; w_++) s += redbuf[w_][tid];
    if (tid >= wg*32 && tid < wg*32+32) s += b2n[1][tid-wg*32];
    pubstore(2, (unsigned)(SEQ+1), tid, s);
    float h2 = pollacc(2, (unsigned)(SEQ+1), tid, s);
    out[((size_t)(b*SEQ + (SEQ-1)))*HD + tid] = h1q[tid] + h2;
  }
}

extern "C" void kernel_launch(void* const* d_in, const int* in_sizes, int n_in,
                              void* d_out, int out_size, void* d_ws, size_t ws_size,
                              hipStream_t stream)
{
  (void)in_sizes; (void)n_in; (void)out_size; (void)ws_size;
  const float* x    = (const float*)d_in[0];
  const float* Wq   = (const float*)d_in[1];
  const float* Wk   = (const float*)d_in[2];
  const float* Wv   = (const float*)d_in[3];
  const float* w_lr = (const float*)d_in[4];
  const float* b_lr = (const float*)d_in[5];
  const float* w_fg = (const float*)d_in[6];
  const float* b_fg = (const float*)d_in[7];
  const float* w_mo = (const float*)d_in[8];
  const float* b_mo = (const float*)d_in[9];
  const float* w1_0 = (const float*)d_in[10];
  const float* b1_0 = (const float*)d_in[11];
  const float* w2_0 = (const float*)d_in[12];
  const float* b2_0 = (const float*)d_in[13];
  const float* m_w1_0 = (const float*)d_in[14];
  const float* m_b1_0 = (const float*)d_in[15];
  const float* m_w2_0 = (const float*)d_in[16];
  const float* m_b2_0 = (const float*)d_in[17];
  const float* w1_1 = (const float*)d_in[18];
  const float* b1_1 = (const float*)d_in[19];
  const float* w2_1 = (const float*)d_in[20];
  const float* b2_1 = (const float*)d_in[21];
  const float* m_w1_1 = (const float*)d_in[22];
  const float* m_b1_1 = (const float*)d_in[23];
  const float* m_w2_1 = (const float*)d_in[24];
  const float* m_b2_1 = (const float*)d_in[25];

  float* wsf = (float*)d_ws;
  unsigned long long* red = (unsigned long long*)d_ws;   // 98304 B of slots
  float* qbuf = wsf + 32768;
  float* kbuf = qbuf + NB*SEQ*HD;
  float* vbuf = kbuf + NB*SEQ*HD;
  float* thb  = vbuf + NB*SEQ*HD;
  float* alb  = thb + NB*SEQ;
  float* etb  = alb + NB*SEQ;
  // ws re-poisoned to 0xAA each launch; 0xAAAAAAAA is never a valid seq tag.

  qkv_kernel<<<dim3(NB*SEQ), dim3(HD), 0, stream>>>(
      x, Wq, Wk, Wv, w_lr, b_lr, w_fg, b_fg, w_mo, b_mo,
      qbuf, kbuf, vbuf, thb, alb, etb);

  scan_kernel<<<dim3(NB*NWG), dim3(512), 0, stream>>>(
      w1_0, b1_0, w2_0, b2_0, m_w1_0, m_b1_0, m_w2_0, m_b2_0,
      w1_1, b1_1, w2_1, b2_1, m_w1_1, m_b1_1, m_w2_1, m_b2_1,
      qbuf, kbuf, vbuf, thb, alb, etb,
      red, (float*)d_out);
}

// Round 4
// 2285.307 us; speedup vs baseline: 2.2781x; 1.1973x over previous
//
#include <hip/hip_runtime.h>

// NeuralMemory scan: B=4, S=256, H=128, EXP=2, DEPTH=2.
// Round 14: R10 base (verified 2392us) + surgical VALU cuts, NO structural
// change. Lessons so far: R11/R12 (layer-1 replication) never got >128 VGPRs
// and is ~net-neutral anyway; R13 (q-deferral into poll windows) regressed
// +345us because phase time = pollers' path (pub + RT) and inserted work
// landed ahead of publishes/polls. The windows have slack only for
// NON-polling waves, and register-resident weights mean no wave can take
// another's work. So: keep R10's schedule byte-identical, cut chain VALU:
//  (1) sigm via raw v_exp_f32/v_rcp_f32 (v_exp IS 2^x): 4 ops vs ~14-20
//      with libm fixups; ~24 calls/step/thread -> ~0.3us/step saved.
//  (2) cache sg1_r/sg2_r (k-path sigmoids) in fwd; bwd derivative reuses
//      instead of recomputing sigm(u1_r)/sigm(u2_r) (8 fewer sigm/step).
//  (3) hoist -th*grad scale factors out of update inner loops.
// Predicted: dur ~2230-2300, VALUBusy ~1.9, absmax ~5e-4 (tiny rounding
// delta from raw rcp/exp, tolerance 1e-3). If dur unchanged -> VALU not
// gating; pivot to RT-latency (slot compaction) next.

constexpr int HD  = 128;   // H
constexpr int SEQ = 256;   // S
constexpr int NB  = 4;     // B
constexpr int ED  = 256;   // H*EXP
constexpr int CW  = 64;    // hidden units per WG per layer (ED/NWG)
constexpr int NWG = 4;     // workgroups per batch

// fast sigmoid: v_exp_f32 computes 2^x, so 1/(1+e^-x) = rcp(1 + 2^(-x*log2e)).
// Raw ops (no denormal/inf fixup chains); |err| ~1ulp, fine vs 1e-3 tol.
__device__ __forceinline__ float sigm(float x){
  float e;
  asm("v_exp_f32 %0, %1" : "=v"(e) : "v"(x * -1.44269504088896f));
  float r;
  asm("v_rcp_f32 %0, %1" : "=v"(r) : "v"(1.0f + e));
  return r;
}

// ---------------- kernel 1: q/k/v + gate scalars ----------------
__global__ __launch_bounds__(128) void qkv_kernel(
    const float* __restrict__ x,
    const float* __restrict__ Wq, const float* __restrict__ Wk, const float* __restrict__ Wv,
    const float* __restrict__ w_lr, const float* __restrict__ b_lr,
    const float* __restrict__ w_fg, const float* __restrict__ b_fg,
    const float* __restrict__ w_mo, const float* __restrict__ b_mo,
    float* __restrict__ qb, float* __restrict__ kb, float* __restrict__ vb,
    float* __restrict__ thb, float* __restrict__ alb, float* __restrict__ etb)
{
  const int bs = blockIdx.x;          // b*SEQ + s
  const int o  = threadIdx.x;         // 0..127
  __shared__ float xl[HD];
  __shared__ float rb[HD];
  xl[o] = x[(size_t)bs*HD + o];
  __syncthreads();

  float aq=0.f, ak=0.f, av=0.f;
  #pragma unroll 8
  for (int i=0;i<HD;i++){
    float xi = xl[i];
    aq = fmaf(xi, Wq[i*HD+o], aq);
    ak = fmaf(xi, Wk[i*HD+o], ak);
    av = fmaf(xi, Wv[i*HD+o], av);
  }
  float sq_ = aq*sigm(aq);
  float sk_ = ak*sigm(ak);
  float sv_ = av*sigm(av);

  auto bsum = [&](float v)->float {
    rb[o] = v; __syncthreads();
    for (int st=64; st>0; st>>=1){
      if (o < st) rb[o] += rb[o+st];
      __syncthreads();
    }
    float r = rb[0];
    __syncthreads();
    return r;
  };

  float nq = bsum(sq_*sq_);
  float nk = bsum(sk_*sk_);
  float dl = bsum(xl[o]*w_lr[o]);
  float df = bsum(xl[o]*w_fg[o]);
  float dm = bsum(xl[o]*w_mo[o]);

  qb[(size_t)bs*HD+o] = sq_ / fmaxf(sqrtf(nq), 1e-12f);
  kb[(size_t)bs*HD+o] = sk_ / fmaxf(sqrtf(nk), 1e-12f);
  vb[(size_t)bs*HD+o] = sv_;
  if (o==0){
    thb[bs] = sigm(dl + b_lr[0]) * 0.01f;   // MAX_LR
    alb[bs] = sigm(df + b_fg[0]);
    etb[bs] = sigm(dm + b_mo[0]);
  }
}

// ---------------- kernel 2: the sequential scan ----------------
__global__ __launch_bounds__(512, 1) void scan_kernel(
    const float* __restrict__ w1_0g, const float* __restrict__ b1_0g,
    const float* __restrict__ w2_0g, const float* __restrict__ b2_0g,
    const float* __restrict__ mw1_0g, const float* __restrict__ mb1_0g,
    const float* __restrict__ mw2_0g, const float* __restrict__ mb2_0g,
    const float* __restrict__ w1_1g, const float* __restrict__ b1_1g,
    const float* __restrict__ w2_1g, const float* __restrict__ b2_1g,
    const float* __restrict__ mw1_1g, const float* __restrict__ mb1_1g,
    const float* __restrict__ mw2_1g, const float* __restrict__ mb2_1g,
    const float* __restrict__ qbuf, const float* __restrict__ kbuf, const float* __restrict__ vbuf,
    const float* __restrict__ thb, const float* __restrict__ alb, const float* __restrict__ etb,
    unsigned long long* __restrict__ red, float* __restrict__ out)
{
  const int bid = blockIdx.x;
  const int b   = bid & 3;     // batch
  const int wg  = bid >> 2;    // 0..3 within batch
  const int tid = threadIdx.x;
  const int iG  = tid & 31;    // i-group (w1) / o-group (w2)
  const int jG  = tid >> 5;    // j-group 0..15
  const int i0  = iG*4;
  const int j0  = jG*4;
  const int c0  = wg*CW;

  __shared__ float pw1L[2][16][512];   // 64 KB p0 (w1), [plane][tid]
  __shared__ float pw2L[2][16][512];   // 64 KB p0 (w2)
  __shared__ float h1k[HD], h1q[HD], h2k[HD], gh1[HD];
  __shared__ float redbuf[8][256];
  __shared__ float b1p[2][CW], b1n[2][CW], b2p[2][32], b2n[2][32];

  // actual weights n = p0*(1-a) + m, carried in registers
  float nw1[2][16], nw2[2][16];
  {
    const float* w1s[2]  = {w1_0g,  w1_1g};
    const float* mw1s[2] = {mw1_0g, mw1_1g};
    const float* w2s[2]  = {w2_0g,  w2_1g};
    const float* mw2s[2] = {mw2_0g, mw2_1g};
    #pragma unroll
    for (int l=0;l<2;l++){
      #pragma unroll
      for (int jj=0;jj<4;jj++){
        #pragma unroll
        for (int ii=0;ii<4;ii++){
          int gi1 = (i0+ii)*ED + (c0+j0+jj);
          float p1 = w1s[l][gi1];
          pw1L[l][jj*4+ii][tid] = p1;
          nw1[l][jj*4+ii] = p1 + mw1s[l][gi1];   // n_{-1} = p0 + m0
          int gi2 = (c0+j0+jj)*HD + (i0+ii);
          float p2 = w2s[l][gi2];
          pw2L[l][jj*4+ii][tid] = p2;
          nw2[l][jj*4+ii] = p2 + mw2s[l][gi2];
        }
      }
    }
  }
  if (tid < CW){
    float p0a = b1_0g[c0+tid], p1a = b1_1g[c0+tid];
    b1p[0][tid] = p0a; b1n[0][tid] = p0a + mb1_0g[c0+tid];
    b1p[1][tid] = p1a; b1n[1][tid] = p1a + mb1_1g[c0+tid];
  } else if (tid < CW+32){
    int oo = tid - CW;
    float p0a = b2_0g[wg*32+oo], p1a = b2_1g[wg*32+oo];
    b2p[0][oo] = p0a; b2n[0][oo] = p0a + mb2_0g[wg*32+oo];
    b2p[1][oo] = p1a; b2n[1][oo] = p1a + mb2_1g[wg*32+oo];
  }

  auto pubstore = [&](int type, unsigned seq, int idx, float val){
    unsigned long long* p = red + (((b*3+type)*NWG + wg)*256 + idx);
    unsigned long long pk = ((unsigned long long)seq << 32) |
                            (unsigned long long)__float_as_uint(val);
    __hip_atomic_store(p, pk, __ATOMIC_RELAXED, __HIP_MEMORY_SCOPE_AGENT);
  };
  auto pollacc = [&](int type, unsigned seq, int idx, float own)->float{
    unsigned long long* base = red + ((b*3+type)*NWG)*256;
    const int wA=((wg+1)&3)*256+idx, wB=((wg+2)&3)*256+idx, wC=((wg+3)&3)*256+idx;
    unsigned long long vA = __hip_atomic_load(base+wA, __ATOMIC_RELAXED, __HIP_MEMORY_SCOPE_AGENT);
    unsigned long long vB = __hip_atomic_load(base+wB, __ATOMIC_RELAXED, __HIP_MEMORY_SCOPE_AGENT);
    unsigned long long vC = __hip_atomic_load(base+wC, __ATOMIC_RELAXED, __HIP_MEMORY_SCOPE_AGENT);
    float s = own; unsigned got = 0;
    while (got != 7u){
      if (!(got&1u)){
        if ((unsigned)(vA>>32)==seq){ s += __uint_as_float((unsigned)vA); got|=1u; }
        else vA = __hip_atomic_load(base+wA, __ATOMIC_RELAXED, __HIP_MEMORY_SCOPE_AGENT);
      }
      if (!(got&2u)){
        if ((unsigned)(vB>>32)==seq){ s += __uint_as_float((unsigned)vB); got|=2u; }
        else vB = __hip_atomic_load(base+wB, __ATOMIC_RELAXED, __HIP_MEMORY_SCOPE_AGENT);
      }
      if (!(got&4u)){
        if ((unsigned)(vC>>32)==seq){ s += __uint_as_float((unsigned)vC); got|=4u; }
        else vC = __hip_atomic_load(base+wC, __ATOMIC_RELAXED, __HIP_MEMORY_SCOPE_AGENT);
      }
    }
    return s;
  };

  // loop-carried per-thread state
  float u1_r[4], s1_r[4], sg1_r[4], u2_r[4], s2_r[4], sg2_r[4], h1k_r[4], v_r[4], vc_r = 0.f;
  float kprev4[4];   // k_t (this step's grad key), i0-range

  // forward from biased layer-0 pre-activations uq/uk.
  // ro = F1 residual (tid<128: q_t[tid]; 128..255: k_{t+1}[tid-128]).
  auto fwdFromU = [&](int t, bool writeOut, unsigned seq,
                      const float* uq, const float* uk, float ro){
    float sq1q[4];
    #pragma unroll
    for (int jj=0;jj<4;jj++){
      float vq = uq[jj], vk = uk[jj];
      u1_r[jj]=vk;
      float sgk = sigm(vk);
      sg1_r[jj]=sgk; s1_r[jj]=vk*sgk;
      sq1q[jj]=vq*sigm(vq);
    }
    // ---- layer0 out partials (nw2[0] = n_t, updated before call) ----
    float oq[4]={0,0,0,0}, ok[4]={0,0,0,0};
    #pragma unroll
    for (int jj=0;jj<4;jj++){
      #pragma unroll
      for (int oo=0;oo<4;oo++){
        float w = nw2[0][jj*4+oo];
        oq[oo] = fmaf(sq1q[jj], w, oq[oo]);
        ok[oo] = fmaf(s1_r[jj], w, ok[oo]);
      }
    }
    #pragma unroll
    for (int oo=0;oo<4;oo++){
      oq[oo] += __shfl_xor(oq[oo], 32, 64);
      ok[oo] += __shfl_xor(ok[oo], 32, 64);
    }
    if (!(tid & 32)){
      int wv = tid>>6;
      #pragma unroll
      for (int oo=0;oo<4;oo++){
        redbuf[wv][i0+oo]     = oq[oo];
        redbuf[wv][128+i0+oo] = ok[oo];
      }
    }
    __syncthreads();                       // S4
    if (tid < 256){
      float p=0.f;
      #pragma unroll
      for (int w_=0; w_<8; w_++) p += redbuf[w_][tid];
      int o = tid & 127;
      if (o >= wg*32 && o < wg*32+32)
        p += b2n[0][o-wg*32];
      pubstore(1, seq, tid, p);
      float s0 = ro + pollacc(1, seq, tid, p);
      if (tid<128) h1q[o]=s0; else h1k[o]=s0;
    }
    __syncthreads();                       // S5
    // ---- layer1 u ----
    float aq2[4]={0,0,0,0}, ak2[4]={0,0,0,0};
    #pragma unroll
    for (int ii=0;ii<4;ii++){
      float qi = h1q[i0+ii], ki = h1k[i0+ii];
      h1k_r[ii] = ki;
      #pragma unroll
      for (int jj=0;jj<4;jj++){
        float w = nw1[1][jj*4+ii];
        aq2[jj] = fmaf(qi, w, aq2[jj]);
        ak2[jj] = fmaf(ki, w, ak2[jj]);
      }
    }
    #pragma unroll
    for (int d=1; d<32; d<<=1){
      #pragma unroll
      for (int jj=0;jj<4;jj++){
        aq2[jj] += __shfl_xor(aq2[jj], d, 64);
        ak2[jj] += __shfl_xor(ak2[jj], d, 64);
      }
    }
    float sq2q[4];
    #pragma unroll
    for (int jj=0;jj<4;jj++){
      float bb = b1n[1][j0+jj];
      float vq = aq2[jj]+bb, vk = ak2[jj]+bb;
      u2_r[jj]=vk;
      float sgk = sigm(vk);
      sg2_r[jj]=sgk; s2_r[jj]=vk*sgk;
      sq2q[jj]=vq*sigm(vq);
    }
    // ---- layer1 out partials ----
    #pragma unroll
    for (int oo=0;oo<4;oo++){ oq[oo]=0.f; ok[oo]=0.f; }
    #pragma unroll
    for (int jj=0;jj<4;jj++){
      #pragma unroll
      for (int oo=0;oo<4;oo++){
        float w = nw2[1][jj*4+oo];
        oq[oo] = fmaf(sq2q[jj], w, oq[oo]);
        ok[oo] = fmaf(s2_r[jj], w, ok[oo]);
      }
    }
    #pragma unroll
    for (int oo=0;oo<4;oo++){
      oq[oo] += __shfl_xor(oq[oo], 32, 64);
      ok[oo] += __shfl_xor(ok[oo], 32, 64);
    }
    if (!(tid & 32)){
      int wv = tid>>6;
      #pragma unroll
      for (int oo=0;oo<4;oo++){
        redbuf[wv][i0+oo]     = oq[oo];
        redbuf[wv][128+i0+oo] = ok[oo];
      }
    }
    __syncthreads();                       // S6
    if (tid < 256){
      float p=0.f;
      #pragma unroll
      for (int w_=0; w_<8; w_++) p += redbuf[w_][tid];
      int o = tid & 127;
      if (o >= wg*32 && o < wg*32+32)
        p += b2n[1][o-wg*32];
      pubstore(2, seq, tid, p);
      float s0 = ((tid<128) ? h1q[o] : h1k[o]) + pollacc(2, seq, tid, p);
      if (tid<128){
        if (writeOut && o >= wg*32 && o < wg*32+32)
          out[((size_t)(b*SEQ + t))*HD + o] = s0;
      } else {
        h2k[o] = s0;
      }
    }
  };

  // ---- prologue: forward k_0 with n_{-1} = p0 + m0 (m0=0 pristine) ----
  {
    #pragma unroll
    for (int ii=0;ii<4;ii++){
      kprev4[ii] = kbuf[((size_t)b*SEQ + 0)*HD + i0+ii];
      v_r[ii]    = vbuf[((size_t)b*SEQ + 0)*HD + i0+ii];
    }
    if (tid < HD) vc_r = vbuf[((size_t)b*SEQ + 0)*HD + tid];
    float ro0 = 0.f;
    if (tid >= 128 && tid < 256)
      ro0 = kbuf[((size_t)b*SEQ + 0)*HD + (tid-128)];
    __syncthreads();   // init (LDS p0/biases) visible
    float ak0[4]={0,0,0,0};
    #pragma unroll
    for (int ii=0;ii<4;ii++){
      float ki = kprev4[ii];
      #pragma unroll
      for (int jj=0;jj<4;jj++)
        ak0[jj] = fmaf(ki, nw1[0][jj*4+ii], ak0[jj]);
    }
    #pragma unroll
    for (int d=1; d<32; d<<=1){
      #pragma unroll
      for (int jj=0;jj<4;jj++) ak0[jj] += __shfl_xor(ak0[jj], d, 64);
    }
    float uq0[4], uk0[4];
    #pragma unroll
    for (int jj=0;jj<4;jj++){
      float bb = b1n[0][j0+jj];
      uq0[jj] = bb;              // q-path = 0 vector (discarded)
      uk0[jj] = ak0[jj] + bb;
    }
    fwdFromU(0, false, 1u, uq0, uk0, ro0);
  }

  float dPrev = 1.f;   // 1 - alpha_{-1}
  for (int t=0; t<SEQ; ++t){
    const int tn = (t < SEQ-1) ? t+1 : SEQ-1;
    // ---- early global loads: q_t, k_{t+1} (hidden under S1 + backward) ----
    float qv4[4], kv4[4];
    #pragma unroll
    for (int ii=0;ii<4;ii++){
      qv4[ii] = qbuf[((size_t)b*SEQ + t )*HD + i0+ii];
      kv4[ii] = kbuf[((size_t)b*SEQ + tn)*HD + i0+ii];
    }
    float ro = 0.f;
    if (tid < 128)      ro = qbuf[((size_t)b*SEQ + t )*HD + tid];
    else if (tid < 256) ro = kbuf[((size_t)b*SEQ + tn)*HD + (tid-128)];
    const float th = thb[b*SEQ+t];
    const float al = alb[b*SEQ+t];
    const float et = etb[b*SEQ+t];
    const float nth = -th;
    const float dcur = 1.f - al;
    const float cP = dcur - et*dPrev;
    __syncthreads();                       // S1: h2k from prev fwd visible
    // ---- g2v, gu2 (weights n_{t-1}) ----
    float g2v_r[4];
    #pragma unroll
    for (int ii=0;ii<4;ii++) g2v_r[ii] = 0.015625f*(h2k[i0+ii] - v_r[ii]);
    float acc[4]={0,0,0,0};
    #pragma unroll
    for (int oo=0;oo<4;oo++){
      float go = g2v_r[oo];
      #pragma unroll
      for (int jj=0;jj<4;jj++)
        acc[jj] = fmaf(go, nw2[1][jj*4+oo], acc[jj]);
    }
    #pragma unroll
    for (int d=1; d<32; d<<=1){
      #pragma unroll
      for (int jj=0;jj<4;jj++) acc[jj] += __shfl_xor(acc[jj], d, 64);
    }
    float gu2r[4];
    #pragma unroll
    for (int jj=0;jj<4;jj++){
      float u=u2_r[jj]; float sg=sg2_r[jj];          // cached from fwd
      gu2r[jj] = acc[jj]*sg*fmaf(u, 1.f-sg, 1.f);
    }
    // ---- gh1 partial ----
    float a2[4]={0,0,0,0};
    #pragma unroll
    for (int jj=0;jj<4;jj++){
      float gj = gu2r[jj];
      #pragma unroll
      for (int ii=0;ii<4;ii++)
        a2[ii] = fmaf(gj, nw1[1][jj*4+ii], a2[ii]);
    }
    #pragma unroll
    for (int ii=0;ii<4;ii++) a2[ii] += __shfl_xor(a2[ii], 32, 64);
    if (!(tid & 32)){
      int wv = tid>>6;
      #pragma unroll
      for (int ii=0;ii<4;ii++) redbuf[wv][i0+ii] = a2[ii];
    }
    __syncthreads();                       // S2
    const unsigned seqB = (unsigned)(t+1);
    float pB = 0.f, g2vc = 0.f;
    if (tid < HD){
      #pragma unroll
      for (int w_=0;w_<8;w_++) pB += redbuf[w_][tid];
      pubstore(0, seqB, tid, pB);          // publish ASAP
      g2vc = 0.015625f*(h2k[tid] - vc_r);
    }
    // ---- B-poll shadow: layer-1 n-updates + v prefetch ----
    {
      float tg2[4], tv2[4];
      #pragma unroll
      for (int jj=0;jj<4;jj++) tg2[jj] = nth*gu2r[jj];
      #pragma unroll
      for (int ii=0;ii<4;ii++) tv2[ii] = nth*g2v_r[ii];
      #pragma unroll
      for (int jj=0;jj<4;jj++){
        float g2jt = tg2[jj], s2j = s2_r[jj];
        #pragma unroll
        for (int ii=0;ii<4;ii++){
          int e = jj*4+ii;
          nw1[1][e] = fmaf(et, nw1[1][e],
                           fmaf(cP, pw1L[1][e][tid], h1k_r[ii]*g2jt));
          nw2[1][e] = fmaf(et, nw2[1][e],
                           fmaf(cP, pw2L[1][e][tid], s2j*tv2[ii]));
        }
      }
      if (iG==0){
        #pragma unroll
        for (int jj=0;jj<4;jj++)
          b1n[1][j0+jj] = fmaf(et, b1n[1][j0+jj],
                               fmaf(cP, b1p[1][j0+jj], tg2[jj]));
      }
      if (jG==0 && iG>=wg*8 && iG<wg*8+8){
        #pragma unroll
        for (int ii=0;ii<4;ii++)
          b2n[1][i0+ii-wg*32] = fmaf(et, b2n[1][i0+ii-wg*32],
                                     fmaf(cP, b2p[1][i0+ii-wg*32], tv2[ii]));
      }
    }
    // prefetch v_{t+1} (old v consumed above)
    #pragma unroll
    for (int ii=0;ii<4;ii++)
      v_r[ii] = vbuf[((size_t)b*SEQ + tn)*HD + i0+ii];
    if (tid < HD) vc_r = vbuf[((size_t)b*SEQ + tn)*HD + tid];
    // ---- poll B ----
    if (tid < HD)
      gh1[tid] = g2vc + pollacc(0, seqB, tid, pB);
    __syncthreads();                       // S3
    // ---- gu1 (weights nw2[0] = n_{t-1}) ----
    float gh1_r[4];
    #pragma unroll
    for (int ii=0;ii<4;ii++) gh1_r[ii] = gh1[i0+ii];
    #pragma unroll
    for (int jj=0;jj<4;jj++) acc[jj]=0.f;
    #pragma unroll
    for (int oo=0;oo<4;oo++){
      float go = gh1_r[oo];
      #pragma unroll
      for (int jj=0;jj<4;jj++)
        acc[jj] = fmaf(go, nw2[0][jj*4+oo], acc[jj]);
    }
    #pragma unroll
    for (int d=1; d<32; d<<=1){
      #pragma unroll
      for (int jj=0;jj<4;jj++) acc[jj] += __shfl_xor(acc[jj], d, 64);
    }
    float gu1r[4];
    #pragma unroll
    for (int jj=0;jj<4;jj++){
      float u=u1_r[jj]; float sg=sg1_r[jj];          // cached from fwd
      gu1r[jj] = acc[jj]*sg*fmaf(u, 1.f-sg, 1.f);
    }
    // ---- layer-0 n-updates (LDS p0 reads) ----
    {
      float tg1[4], tv0[4];
      #pragma unroll
      for (int jj=0;jj<4;jj++) tg1[jj] = nth*gu1r[jj];
      #pragma unroll
      for (int ii=0;ii<4;ii++) tv0[ii] = nth*gh1_r[ii];
      #pragma unroll
      for (int jj=0;jj<4;jj++){
        float g1jt = tg1[jj], s1j = s1_r[jj];
        #pragma unroll
        for (int ii=0;ii<4;ii++){
          int e = jj*4+ii;
          nw1[0][e] = fmaf(et, nw1[0][e],
                           fmaf(cP, pw1L[0][e][tid], kprev4[ii]*g1jt));
          nw2[0][e] = fmaf(et, nw2[0][e],
                           fmaf(cP, pw2L[0][e][tid], s1j*tv0[ii]));
        }
      }
      if (iG==0){
        #pragma unroll
        for (int jj=0;jj<4;jj++)
          b1n[0][j0+jj] = fmaf(et, b1n[0][j0+jj],
                               fmaf(cP, b1p[0][j0+jj], tg1[jj]));
      }
      if (jG==0 && iG>=wg*8 && iG<wg*8+8){
        #pragma unroll
        for (int ii=0;ii<4;ii++)
          b2n[0][i0+ii-wg*32] = fmaf(et, b2n[0][i0+ii-wg*32],
                                     fmaf(cP, b2p[0][i0+ii-wg*32], tv0[ii]));
      }
    }
    // ---- layer-0 dual u with updated n_t (register q/k inputs) ----
    float aq[4]={0,0,0,0}, ak[4]={0,0,0,0};
    #pragma unroll
    for (int ii=0;ii<4;ii++){
      float qi = qv4[ii], ki = kv4[ii];
      #pragma unroll
      for (int jj=0;jj<4;jj++){
        float w = nw1[0][jj*4+ii];
        aq[jj] = fmaf(qi, w, aq[jj]);
        ak[jj] = fmaf(ki, w, ak[jj]);
      }
    }
    #pragma unroll
    for (int d=1; d<32; d<<=1){
      #pragma unroll
      for (int jj=0;jj<4;jj++){
        aq[jj] += __shfl_xor(aq[jj], d, 64);
        ak[jj] += __shfl_xor(ak[jj], d, 64);
      }
    }
    float uqf[4], ukf[4];
    #pragma unroll
    for (int jj=0;jj<4;jj++){
      float bb = b1n[0][j0+jj];   // wave-local RAW (writer iG==0 same wave)
      uqf[jj] = aq[jj] + bb;
      ukf[jj] = ak[jj] + bb;
    }
    #pragma unroll
    for (int ii=0;ii<4;ii++) kprev4[ii] = kv4[ii];   // k~ for next step
    dPrev = dcur;
    fwdFromU(t, true, (unsigned)(t+2), uqf, ukf, ro);
  }
}

extern "C" void kernel_launch(void* const* d_in, const int* in_sizes, int n_in,
                              void* d_out, int out_size, void* d_ws, size_t ws_size,
                              hipStream_t stream)
{
  (void)in_sizes; (void)n_in; (void)out_size; (void)ws_size;
  const float* x    = (const float*)d_in[0];
  const float* Wq   = (const float*)d_in[1];
  const float* Wk   = (const float*)d_in[2];
  const float* Wv   = (const float*)d_in[3];
  const float* w_lr = (const float*)d_in[4];
  const float* b_lr = (const float*)d_in[5];
  const float* w_fg = (const float*)d_in[6];
  const float* b_fg = (const float*)d_in[7];
  const float* w_mo = (const float*)d_in[8];
  const float* b_mo = (const float*)d_in[9];
  const float* w1_0 = (const float*)d_in[10];
  const float* b1_0 = (const float*)d_in[11];
  const float* w2_0 = (const float*)d_in[12];
  const float* b2_0 = (const float*)d_in[13];
  const float* m_w1_0 = (const float*)d_in[14];
  const float* m_b1_0 = (const float*)d_in[15];
  const float* m_w2_0 = (const float*)d_in[16];
  const float* m_b2_0 = (const float*)d_in[17];
  const float* w1_1 = (const float*)d_in[18];
  const float* b1_1 = (const float*)d_in[19];
  const float* w2_1 = (const float*)d_in[20];
  const float* b2_1 = (const float*)d_in[21];
  const float* m_w1_1 = (const float*)d_in[22];
  const float* m_b1_1 = (const float*)d_in[23];
  const float* m_w2_1 = (const float*)d_in[24];
  const float* m_b2_1 = (const float*)d_in[25];

  float* wsf = (float*)d_ws;
  unsigned long long* red = (unsigned long long*)d_ws;   // 98304 B of slots
  float* qbuf = wsf + 32768;
  float* kbuf = qbuf + NB*SEQ*HD;
  float* vbuf = kbuf + NB*SEQ*HD;
  float* thb  = vbuf + NB*SEQ*HD;
  float* alb  = thb + NB*SEQ;
  float* etb  = alb + NB*SEQ;
  // ws re-poisoned to 0xAA each launch; 0xAAAAAAAA is never a valid seq tag.

  qkv_kernel<<<dim3(NB*SEQ), dim3(HD), 0, stream>>>(
      x, Wq, Wk, Wv, w_lr, b_lr, w_fg, b_fg, w_mo, b_mo,
      qbuf, kbuf, vbuf, thb, alb, etb);

  scan_kernel<<<dim3(NB*NWG), dim3(512), 0, stream>>>(
      w1_0, b1_0, w2_0, b2_0, m_w1_0, m_b1_0, m_w2_0, m_b2_0,
      w1_1, b1_1, w2_1, b2_1, m_w1_1, m_b1_1, m_w2_1, m_b2_1,
      qbuf, kbuf, vbuf, thb, alb, etb,
      red, (float*)d_out);
}

// Round 6
// 1932.363 us; speedup vs baseline: 2.6941x; 1.1826x over previous
//
#include <hip/hip_runtime.h>

// NeuralMemory scan: B=4, S=256, H=128, EXP=2, DEPTH=2.
// Round 16: R15 retry — fix compile error only. __builtin_amdgcn_update_dpp
// needs a CONSTANT ctrl at the call site; runtime function arg (even
// forceinlined) is rejected. ctrl is now a template parameter.
// Content identical to R15 otherwise:
//  (A) scan: wave reduces via DPP butterflies (quad_perm ^1, ^2,
//      row_half_mirror, row_mirror, then ds_swizzle ^16) instead of 5-level
//      ds_bpermute chains (~300cy -> ~90cy per reduce site; 4 on-chain
//      sites/step).
//  (B) qkv: 8 tokens/block, W streamed once per block (24MB total vs 192MB),
//      wave DPP reduces + 2 barriers/token.
// Predicted: scan steady 2176 -> ~2060-2120; bench 2285 -> ~2100-2180.

constexpr int HD  = 128;   // H
constexpr int SEQ = 256;   // S
constexpr int NB  = 4;     // B
constexpr int ED  = 256;   // H*EXP
constexpr int CW  = 64;    // hidden units per WG per layer (ED/NWG)
constexpr int NWG = 4;     // workgroups per batch
constexpr int TOK = 8;     // tokens per qkv block

// fast sigmoid: v_exp_f32 computes 2^x, so 1/(1+e^-x) = rcp(1 + 2^(-x*log2e)).
__device__ __forceinline__ float sigm(float x){
  float e;
  asm("v_exp_f32 %0, %1" : "=v"(e) : "v"(x * -1.44269504088896f));
  float r;
  asm("v_rcp_f32 %0, %1" : "=v"(r) : "v"(1.0f + e));
  return r;
}

// DPP-add helper: x + perm(x); ctrl must be a compile-time constant.
template<int CTRL>
__device__ __forceinline__ float dpp_add(float x){
  int y = __builtin_amdgcn_update_dpp(0, __float_as_int(x), CTRL, 0xF, 0xF, true);
  return x + __int_as_float(y);
}
// sum over each 32-lane group (bits 0..4), result in all lanes.
// Stages: ^1 (quad_perm 1,0,3,2 = 0xB1), ^2 (quad_perm 2,3,0,1 = 0x4E),
// pair-4s (row_half_mirror 0x141), pair-8s (row_mirror 0x140),
// ^16 within 32 (ds_swizzle BitMode xor=0x10, and=0x1F -> 0x401F).
__device__ __forceinline__ float red32(float x){
  x = dpp_add<0xB1>(x);
  x = dpp_add<0x4E>(x);
  x = dpp_add<0x141>(x);
  x = dpp_add<0x140>(x);
  x += __int_as_float(__builtin_amdgcn_ds_swizzle(__float_as_int(x), 0x401F));
  return x;
}
__device__ __forceinline__ float red64(float x){
  x = red32(x);
  x += __shfl_xor(x, 32, 64);
  return x;
}

// ---------------- kernel 1: q/k/v + gate scalars (8 tokens/block) ----------------
__global__ __launch_bounds__(128) void qkv_kernel(
    const float* __restrict__ x,
    const float* __restrict__ Wq, const float* __restrict__ Wk, const float* __restrict__ Wv,
    const float* __restrict__ w_lr, const float* __restrict__ b_lr,
    const float* __restrict__ w_fg, const float* __restrict__ b_fg,
    const float* __restrict__ w_mo, const float* __restrict__ b_mo,
    float* __restrict__ qb, float* __restrict__ kb, float* __restrict__ vb,
    float* __restrict__ thb, float* __restrict__ alb, float* __restrict__ etb)
{
  const int t0 = blockIdx.x * TOK;    // first flattened token (b*SEQ+s)
  const int o  = threadIdx.x;         // 0..127
  __shared__ float xl[TOK][HD];
  __shared__ float red2[2][8];        // cross-wave partials

  #pragma unroll
  for (int tt=0; tt<TOK; ++tt)
    xl[tt][o] = x[(size_t)(t0+tt)*HD + o];
  const float wl = w_lr[o], wf = w_fg[o], wm = w_mo[o];
  const float blr = b_lr[0], bfg = b_fg[0], bmo = b_mo[0];
  __syncthreads();

  float aq[TOK], ak[TOK], av[TOK];
  #pragma unroll
  for (int tt=0; tt<TOK; ++tt){ aq[tt]=0.f; ak[tt]=0.f; av[tt]=0.f; }
  for (int i=0; i<HD; i+=4){
    float wq0=Wq[(i+0)*HD+o], wk0=Wk[(i+0)*HD+o], wv0=Wv[(i+0)*HD+o];
    float wq1=Wq[(i+1)*HD+o], wk1=Wk[(i+1)*HD+o], wv1=Wv[(i+1)*HD+o];
    float wq2=Wq[(i+2)*HD+o], wk2=Wk[(i+2)*HD+o], wv2=Wv[(i+2)*HD+o];
    float wq3=Wq[(i+3)*HD+o], wk3=Wk[(i+3)*HD+o], wv3=Wv[(i+3)*HD+o];
    #pragma unroll
    for (int tt=0; tt<TOK; ++tt){
      float4 xv = *reinterpret_cast<const float4*>(&xl[tt][i]);
      aq[tt]=fmaf(xv.x,wq0,aq[tt]); ak[tt]=fmaf(xv.x,wk0,ak[tt]); av[tt]=fmaf(xv.x,wv0,av[tt]);
      aq[tt]=fmaf(xv.y,wq1,aq[tt]); ak[tt]=fmaf(xv.y,wk1,ak[tt]); av[tt]=fmaf(xv.y,wv1,av[tt]);
      aq[tt]=fmaf(xv.z,wq2,aq[tt]); ak[tt]=fmaf(xv.z,wk2,ak[tt]); av[tt]=fmaf(xv.z,wv2,av[tt]);
      aq[tt]=fmaf(xv.w,wq3,aq[tt]); ak[tt]=fmaf(xv.w,wk3,ak[tt]); av[tt]=fmaf(xv.w,wv3,av[tt]);
    }
  }
  #pragma unroll
  for (int tt=0; tt<TOK; ++tt){
    const size_t idx = (size_t)(t0+tt);
    float a_q=aq[tt], a_k=ak[tt], a_v=av[tt];
    float sq_ = a_q*sigm(a_q);
    float sk_ = a_k*sigm(a_k);
    float sv_ = a_v*sigm(a_v);
    float xo = xl[tt][o];
    float p0 = red64(sq_*sq_);
    float p1 = red64(sk_*sk_);
    float p2 = red64(xo*wl);
    float p3 = red64(xo*wf);
    float p4 = red64(xo*wm);
    if ((o&63)==0){
      int w = o>>6;
      red2[w][0]=p0; red2[w][1]=p1; red2[w][2]=p2; red2[w][3]=p3; red2[w][4]=p4;
    }
    __syncthreads();
    float nq = red2[0][0]+red2[1][0];
    float nk = red2[0][1]+red2[1][1];
    qb[idx*HD+o] = sq_ / fmaxf(sqrtf(nq), 1e-12f);
    kb[idx*HD+o] = sk_ / fmaxf(sqrtf(nk), 1e-12f);
    vb[idx*HD+o] = sv_;
    if (o==0){
      float dl = red2[0][2]+red2[1][2];
      float df = red2[0][3]+red2[1][3];
      float dm = red2[0][4]+red2[1][4];
      thb[idx] = sigm(dl + blr) * 0.01f;   // MAX_LR
      alb[idx] = sigm(df + bfg);
      etb[idx] = sigm(dm + bmo);
    }
    __syncthreads();   // red2 reuse next token
  }
}

// ---------------- kernel 2: the sequential scan ----------------
__global__ __launch_bounds__(512, 1) void scan_kernel(
    const float* __restrict__ w1_0g, const float* __restrict__ b1_0g,
    const float* __restrict__ w2_0g, const float* __restrict__ b2_0g,
    const float* __restrict__ mw1_0g, const float* __restrict__ mb1_0g,
    const float* __restrict__ mw2_0g, const float* __restrict__ mb2_0g,
    const float* __restrict__ w1_1g, const float* __restrict__ b1_1g,
    const float* __restrict__ w2_1g, const float* __restrict__ b2_1g,
    const float* __restrict__ mw1_1g, const float* __restrict__ mb1_1g,
    const float* __restrict__ mw2_1g, const float* __restrict__ mb2_1g,
    const float* __restrict__ qbuf, const float* __restrict__ kbuf, const float* __restrict__ vbuf,
    const float* __restrict__ thb, const float* __restrict__ alb, const float* __restrict__ etb,
    unsigned long long* __restrict__ red, float* __restrict__ out)
{
  const int bid = blockIdx.x;
  const int b   = bid & 3;     // batch
  const int wg  = bid >> 2;    // 0..3 within batch
  const int tid = threadIdx.x;
  const int iG  = tid & 31;    // i-group (w1) / o-group (w2)
  const int jG  = tid >> 5;    // j-group 0..15
  const int i0  = iG*4;
  const int j0  = jG*4;
  const int c0  = wg*CW;

  __shared__ float pw1L[2][16][512];   // 64 KB p0 (w1), [plane][tid]
  __shared__ float pw2L[2][16][512];   // 64 KB p0 (w2)
  __shared__ float h1k[HD], h1q[HD], h2k[HD], gh1[HD];
  __shared__ float redbuf[8][256];
  __shared__ float b1p[2][CW], b1n[2][CW], b2p[2][32], b2n[2][32];

  // actual weights n = p0*(1-a) + m, carried in registers
  float nw1[2][16], nw2[2][16];
  {
    const float* w1s[2]  = {w1_0g,  w1_1g};
    const float* mw1s[2] = {mw1_0g, mw1_1g};
    const float* w2s[2]  = {w2_0g,  w2_1g};
    const float* mw2s[2] = {mw2_0g, mw2_1g};
    #pragma unroll
    for (int l=0;l<2;l++){
      #pragma unroll
      for (int jj=0;jj<4;jj++){
        #pragma unroll
        for (int ii=0;ii<4;ii++){
          int gi1 = (i0+ii)*ED + (c0+j0+jj);
          float p1 = w1s[l][gi1];
          pw1L[l][jj*4+ii][tid] = p1;
          nw1[l][jj*4+ii] = p1 + mw1s[l][gi1];   // n_{-1} = p0 + m0
          int gi2 = (c0+j0+jj)*HD + (i0+ii);
          float p2 = w2s[l][gi2];
          pw2L[l][jj*4+ii][tid] = p2;
          nw2[l][jj*4+ii] = p2 + mw2s[l][gi2];
        }
      }
    }
  }
  if (tid < CW){
    float p0a = b1_0g[c0+tid], p1a = b1_1g[c0+tid];
    b1p[0][tid] = p0a; b1n[0][tid] = p0a + mb1_0g[c0+tid];
    b1p[1][tid] = p1a; b1n[1][tid] = p1a + mb1_1g[c0+tid];
  } else if (tid < CW+32){
    int oo = tid - CW;
    float p0a = b2_0g[wg*32+oo], p1a = b2_1g[wg*32+oo];
    b2p[0][oo] = p0a; b2n[0][oo] = p0a + mb2_0g[wg*32+oo];
    b2p[1][oo] = p1a; b2n[1][oo] = p1a + mb2_1g[wg*32+oo];
  }

  auto pubstore = [&](int type, unsigned seq, int idx, float val){
    unsigned long long* p = red + (((b*3+type)*NWG + wg)*256 + idx);
    unsigned long long pk = ((unsigned long long)seq << 32) |
                            (unsigned long long)__float_as_uint(val);
    __hip_atomic_store(p, pk, __ATOMIC_RELAXED, __HIP_MEMORY_SCOPE_AGENT);
  };
  auto pollacc = [&](int type, unsigned seq, int idx, float own)->float{
    unsigned long long* base = red + ((b*3+type)*NWG)*256;
    const int wA=((wg+1)&3)*256+idx, wB=((wg+2)&3)*256+idx, wC=((wg+3)&3)*256+idx;
    unsigned long long vA = __hip_atomic_load(base+wA, __ATOMIC_RELAXED, __HIP_MEMORY_SCOPE_AGENT);
    unsigned long long vB = __hip_atomic_load(base+wB, __ATOMIC_RELAXED, __HIP_MEMORY_SCOPE_AGENT);
    unsigned long long vC = __hip_atomic_load(base+wC, __ATOMIC_RELAXED, __HIP_MEMORY_SCOPE_AGENT);
    float s = own; unsigned got = 0;
    while (got != 7u){
      if (!(got&1u)){
        if ((unsigned)(vA>>32)==seq){ s += __uint_as_float((unsigned)vA); got|=1u; }
        else vA = __hip_atomic_load(base+wA, __ATOMIC_RELAXED, __HIP_MEMORY_SCOPE_AGENT);
      }
      if (!(got&2u)){
        if ((unsigned)(vB>>32)==seq){ s += __uint_as_float((unsigned)vB); got|=2u; }
        else vB = __hip_atomic_load(base+wB, __ATOMIC_RELAXED, __HIP_MEMORY_SCOPE_AGENT);
      }
      if (!(got&4u)){
        if ((unsigned)(vC>>32)==seq){ s += __uint_as_float((unsigned)vC); got|=4u; }
        else vC = __hip_atomic_load(base+wC, __ATOMIC_RELAXED, __HIP_MEMORY_SCOPE_AGENT);
      }
    }
    return s;
  };

  // loop-carried per-thread state
  float u1_r[4], s1_r[4], sg1_r[4], u2_r[4], s2_r[4], sg2_r[4], h1k_r[4], v_r[4], vc_r = 0.f;
  float kprev4[4];   // k_t (this step's grad key), i0-range

  // forward from biased layer-0 pre-activations uq/uk.
  // ro = F1 residual (tid<128: q_t[tid]; 128..255: k_{t+1}[tid-128]).
  auto fwdFromU = [&](int t, bool writeOut, unsigned seq,
                      const float* uq, const float* uk, float ro){
    float sq1q[4];
    #pragma unroll
    for (int jj=0;jj<4;jj++){
      float vq = uq[jj], vk = uk[jj];
      u1_r[jj]=vk;
      float sgk = sigm(vk);
      sg1_r[jj]=sgk; s1_r[jj]=vk*sgk;
      sq1q[jj]=vq*sigm(vq);
    }
    // ---- layer0 out partials (nw2[0] = n_t, updated before call) ----
    float oq[4]={0,0,0,0}, ok[4]={0,0,0,0};
    #pragma unroll
    for (int jj=0;jj<4;jj++){
      #pragma unroll
      for (int oo=0;oo<4;oo++){
        float w = nw2[0][jj*4+oo];
        oq[oo] = fmaf(sq1q[jj], w, oq[oo]);
        ok[oo] = fmaf(s1_r[jj], w, ok[oo]);
      }
    }
    #pragma unroll
    for (int oo=0;oo<4;oo++){
      oq[oo] += __shfl_xor(oq[oo], 32, 64);
      ok[oo] += __shfl_xor(ok[oo], 32, 64);
    }
    if (!(tid & 32)){
      int wv = tid>>6;
      #pragma unroll
      for (int oo=0;oo<4;oo++){
        redbuf[wv][i0+oo]     = oq[oo];
        redbuf[wv][128+i0+oo] = ok[oo];
      }
    }
    __syncthreads();                       // S4
    if (tid < 256){
      float p=0.f;
      #pragma unroll
      for (int w_=0; w_<8; w_++) p += redbuf[w_][tid];
      int o = tid & 127;
      if (o >= wg*32 && o < wg*32+32)
        p += b2n[0][o-wg*32];
      pubstore(1, seq, tid, p);
      float s0 = ro + pollacc(1, seq, tid, p);
      if (tid<128) h1q[o]=s0; else h1k[o]=s0;
    }
    __syncthreads();                       // S5
    // ---- layer1 u ----
    float aq2[4]={0,0,0,0}, ak2[4]={0,0,0,0};
    #pragma unroll
    for (int ii=0;ii<4;ii++){
      float qi = h1q[i0+ii], ki = h1k[i0+ii];
      h1k_r[ii] = ki;
      #pragma unroll
      for (int jj=0;jj<4;jj++){
        float w = nw1[1][jj*4+ii];
        aq2[jj] = fmaf(qi, w, aq2[jj]);
        ak2[jj] = fmaf(ki, w, ak2[jj]);
      }
    }
    #pragma unroll
    for (int jj=0;jj<4;jj++){
      aq2[jj] = red32(aq2[jj]);
      ak2[jj] = red32(ak2[jj]);
    }
    float sq2q[4];
    #pragma unroll
    for (int jj=0;jj<4;jj++){
      float bb = b1n[1][j0+jj];
      float vq = aq2[jj]+bb, vk = ak2[jj]+bb;
      u2_r[jj]=vk;
      float sgk = sigm(vk);
      sg2_r[jj]=sgk; s2_r[jj]=vk*sgk;
      sq2q[jj]=vq*sigm(vq);
    }
    // ---- layer1 out partials ----
    #pragma unroll
    for (int oo=0;oo<4;oo++){ oq[oo]=0.f; ok[oo]=0.f; }
    #pragma unroll
    for (int jj=0;jj<4;jj++){
      #pragma unroll
      for (int oo=0;oo<4;oo++){
        float w = nw2[1][jj*4+oo];
        oq[oo] = fmaf(sq2q[jj], w, oq[oo]);
        ok[oo] = fmaf(s2_r[jj], w, ok[oo]);
      }
    }
    #pragma unroll
    for (int oo=0;oo<4;oo++){
      oq[oo] += __shfl_xor(oq[oo], 32, 64);
      ok[oo] += __shfl_xor(ok[oo], 32, 64);
    }
    if (!(tid & 32)){
      int wv = tid>>6;
      #pragma unroll
      for (int oo=0;oo<4;oo++){
        redbuf[wv][i0+oo]     = oq[oo];
        redbuf[wv][128+i0+oo] = ok[oo];
      }
    }
    __syncthreads();                       // S6
    if (tid < 256){
      float p=0.f;
      #pragma unroll
      for (int w_=0; w_<8; w_++) p += redbuf[w_][tid];
      int o = tid & 127;
      if (o >= wg*32 && o < wg*32+32)
        p += b2n[1][o-wg*32];
      pubstore(2, seq, tid, p);
      float s0 = ((tid<128) ? h1q[o] : h1k[o]) + pollacc(2, seq, tid, p);
      if (tid<128){
        if (writeOut && o >= wg*32 && o < wg*32+32)
          out[((size_t)(b*SEQ + t))*HD + o] = s0;
      } else {
        h2k[o] = s0;
      }
    }
  };

  // ---- prologue: forward k_0 with n_{-1} = p0 + m0 (m0=0 pristine) ----
  {
    #pragma unroll
    for (int ii=0;ii<4;ii++){
      kprev4[ii] = kbuf[((size_t)b*SEQ + 0)*HD + i0+ii];
      v_r[ii]    = vbuf[((size_t)b*SEQ + 0)*HD + i0+ii];
    }
    if (tid < HD) vc_r = vbuf[((size_t)b*SEQ + 0)*HD + tid];
    float ro0 = 0.f;
    if (tid >= 128 && tid < 256)
      ro0 = kbuf[((size_t)b*SEQ + 0)*HD + (tid-128)];
    __syncthreads();   // init (LDS p0/biases) visible
    float ak0[4]={0,0,0,0};
    #pragma unroll
    for (int ii=0;ii<4;ii++){
      float ki = kprev4[ii];
      #pragma unroll
      for (int jj=0;jj<4;jj++)
        ak0[jj] = fmaf(ki, nw1[0][jj*4+ii], ak0[jj]);
    }
    #pragma unroll
    for (int jj=0;jj<4;jj++) ak0[jj] = red32(ak0[jj]);
    float uq0[4], uk0[4];
    #pragma unroll
    for (int jj=0;jj<4;jj++){
      float bb = b1n[0][j0+jj];
      uq0[jj] = bb;              // q-path = 0 vector (discarded)
      uk0[jj] = ak0[jj] + bb;
    }
    fwdFromU(0, false, 1u, uq0, uk0, ro0);
  }

  float dPrev = 1.f;   // 1 - alpha_{-1}
  for (int t=0; t<SEQ; ++t){
    const int tn = (t < SEQ-1) ? t+1 : SEQ-1;
    // ---- early global loads: q_t, k_{t+1} (hidden under S1 + backward) ----
    float qv4[4], kv4[4];
    #pragma unroll
    for (int ii=0;ii<4;ii++){
      qv4[ii] = qbuf[((size_t)b*SEQ + t )*HD + i0+ii];
      kv4[ii] = kbuf[((size_t)b*SEQ + tn)*HD + i0+ii];
    }
    float ro = 0.f;
    if (tid < 128)      ro = qbuf[((size_t)b*SEQ + t )*HD + tid];
    else if (tid < 256) ro = kbuf[((size_t)b*SEQ + tn)*HD + (tid-128)];
    const float th = thb[b*SEQ+t];
    const float al = alb[b*SEQ+t];
    const float et = etb[b*SEQ+t];
    const float nth = -th;
    const float dcur = 1.f - al;
    const float cP = dcur - et*dPrev;
    __syncthreads();                       // S1: h2k from prev fwd visible
    // ---- g2v, gu2 (weights n_{t-1}) ----
    float g2v_r[4];
    #pragma unroll
    for (int ii=0;ii<4;ii++) g2v_r[ii] = 0.015625f*(h2k[i0+ii] - v_r[ii]);
    float acc[4]={0,0,0,0};
    #pragma unroll
    for (int oo=0;oo<4;oo++){
      float go = g2v_r[oo];
      #pragma unroll
      for (int jj=0;jj<4;jj++)
        acc[jj] = fmaf(go, nw2[1][jj*4+oo], acc[jj]);
    }
    #pragma unroll
    for (int jj=0;jj<4;jj++) acc[jj] = red32(acc[jj]);
    float gu2r[4];
    #pragma unroll
    for (int jj=0;jj<4;jj++){
      float u=u2_r[jj]; float sg=sg2_r[jj];          // cached from fwd
      gu2r[jj] = acc[jj]*sg*fmaf(u, 1.f-sg, 1.f);
    }
    // ---- gh1 partial ----
    float a2[4]={0,0,0,0};
    #pragma unroll
    for (int jj=0;jj<4;jj++){
      float gj = gu2r[jj];
      #pragma unroll
      for (int ii=0;ii<4;ii++)
        a2[ii] = fmaf(gj, nw1[1][jj*4+ii], a2[ii]);
    }
    #pragma unroll
    for (int ii=0;ii<4;ii++) a2[ii] += __shfl_xor(a2[ii], 32, 64);
    if (!(tid & 32)){
      int wv = tid>>6;
      #pragma unroll
      for (int ii=0;ii<4;ii++) redbuf[wv][i0+ii] = a2[ii];
    }
    __syncthreads();                       // S2
    const unsigned seqB = (unsigned)(t+1);
    float pB = 0.f, g2vc = 0.f;
    if (tid < HD){
      #pragma unroll
      for (int w_=0;w_<8;w_++) pB += redbuf[w_][tid];
      pubstore(0, seqB, tid, pB);          // publish ASAP
      g2vc = 0.015625f*(h2k[tid] - vc_r);
    }
    // ---- B-poll shadow: layer-1 n-updates + v prefetch ----
    {
      float tg2[4], tv2[4];
      #pragma unroll
      for (int jj=0;jj<4;jj++) tg2[jj] = nth*gu2r[jj];
      #pragma unroll
      for (int ii=0;ii<4;ii++) tv2[ii] = nth*g2v_r[ii];
      #pragma unroll
      for (int jj=0;jj<4;jj++){
        float g2jt = tg2[jj], s2j = s2_r[jj];
        #pragma unroll
        for (int ii=0;ii<4;ii++){
          int e = jj*4+ii;
          nw1[1][e] = fmaf(et, nw1[1][e],
                           fmaf(cP, pw1L[1][e][tid], h1k_r[ii]*g2jt));
          nw2[1][e] = fmaf(et, nw2[1][e],
                           fmaf(cP, pw2L[1][e][tid], s2j*tv2[ii]));
        }
      }
      if (iG==0){
        #pragma unroll
        for (int jj=0;jj<4;jj++)
          b1n[1][j0+jj] = fmaf(et, b1n[1][j0+jj],
                               fmaf(cP, b1p[1][j0+jj], tg2[jj]));
      }
      if (jG==0 && iG>=wg*8 && iG<wg*8+8){
        #pragma unroll
        for (int ii=0;ii<4;ii++)
          b2n[1][i0+ii-wg*32] = fmaf(et, b2n[1][i0+ii-wg*32],
                                     fmaf(cP, b2p[1][i0+ii-wg*32], tv2[ii]));
      }
    }
    // prefetch v_{t+1} (old v consumed above)
    #pragma unroll
    for (int ii=0;ii<4;ii++)
      v_r[ii] = vbuf[((size_t)b*SEQ + tn)*HD + i0+ii];
    if (tid < HD) vc_r = vbuf[((size_t)b*SEQ + tn)*HD + tid];
    // ---- poll B ----
    if (tid < HD)
      gh1[tid] = g2vc + pollacc(0, seqB, tid, pB);
    __syncthreads();                       // S3
    // ---- gu1 (weights nw2[0] = n_{t-1}) ----
    float gh1_r[4];
    #pragma unroll
    for (int ii=0;ii<4;ii++) gh1_r[ii] = gh1[i0+ii];
    #pragma unroll
    for (int jj=0;jj<4;jj++) acc[jj]=0.f;
    #pragma unroll
    for (int oo=0;oo<4;oo++){
      float go = gh1_r[oo];
      #pragma unroll
      for (int jj=0;jj<4;jj++)
        acc[jj] = fmaf(go, nw2[0][jj*4+oo], acc[jj]);
    }
    #pragma unroll
    for (int jj=0;jj<4;jj++) acc[jj] = red32(acc[jj]);
    float gu1r[4];
    #pragma unroll
    for (int jj=0;jj<4;jj++){
      float u=u1_r[jj]; float sg=sg1_r[jj];          // cached from fwd
      gu1r[jj] = acc[jj]*sg*fmaf(u, 1.f-sg, 1.f);
    }
    // ---- layer-0 n-updates (LDS p0 reads) ----
    {
      float tg1[4], tv0[4];
      #pragma unroll
      for (int jj=0;jj<4;jj++) tg1[jj] = nth*gu1r[jj];
      #pragma unroll
      for (int ii=0;ii<4;ii++) tv0[ii] = nth*gh1_r[ii];
      #pragma unroll
      for (int jj=0;jj<4;jj++){
        float g1jt = tg1[jj], s1j = s1_r[jj];
        #pragma unroll
        for (int ii=0;ii<4;ii++){
          int e = jj*4+ii;
          nw1[0][e] = fmaf(et, nw1[0][e],
                           fmaf(cP, pw1L[0][e][tid], kprev4[ii]*g1jt));
          nw2[0][e] = fmaf(et, nw2[0][e],
                           fmaf(cP, pw2L[0][e][tid], s1j*tv0[ii]));
        }
      }
      if (iG==0){
        #pragma unroll
        for (int jj=0;jj<4;jj++)
          b1n[0][j0+jj] = fmaf(et, b1n[0][j0+jj],
                               fmaf(cP, b1p[0][j0+jj], tg1[jj]));
      }
      if (jG==0 && iG>=wg*8 && iG<wg*8+8){
        #pragma unroll
        for (int ii=0;ii<4;ii++)
          b2n[0][i0+ii-wg*32] = fmaf(et, b2n[0][i0+ii-wg*32],
                                     fmaf(cP, b2p[0][i0+ii-wg*32], tv0[ii]));
      }
    }
    // ---- layer-0 dual u with updated n_t (register q/k inputs) ----
    float aq[4]={0,0,0,0}, ak[4]={0,0,0,0};
    #pragma unroll
    for (int ii=0;ii<4;ii++){
      float qi = qv4[ii], ki = kv4[ii];
      #pragma unroll
      for (int jj=0;jj<4;jj++){
        float w = nw1[0][jj*4+ii];
        aq[jj] = fmaf(qi, w, aq[jj]);
        ak[jj] = fmaf(ki, w, ak[jj]);
      }
    }
    #pragma unroll
    for (int jj=0;jj<4;jj++){
      aq[jj] = red32(aq[jj]);
      ak[jj] = red32(ak[jj]);
    }
    float uqf[4], ukf[4];
    #pragma unroll
    for (int jj=0;jj<4;jj++){
      float bb = b1n[0][j0+jj];   // wave-local RAW (writer iG==0 same wave)
      uqf[jj] = aq[jj] + bb;
      ukf[jj] = ak[jj] + bb;
    }
    #pragma unroll
    for (int ii=0;ii<4;ii++) kprev4[ii] = kv4[ii];   // k~ for next step
    dPrev = dcur;
    fwdFromU(t, true, (unsigned)(t+2), uqf, ukf, ro);
  }
}

extern "C" void kernel_launch(void* const* d_in, const int* in_sizes, int n_in,
                              void* d_out, int out_size, void* d_ws, size_t ws_size,
                              hipStream_t stream)
{
  (void)in_sizes; (void)n_in; (void)out_size; (void)ws_size;
  const float* x    = (const float*)d_in[0];
  const float* Wq   = (const float*)d_in[1];
  const float* Wk   = (const float*)d_in[2];
  const float* Wv   = (const float*)d_in[3];
  const float* w_lr = (const float*)d_in[4];
  const float* b_lr = (const float*)d_in[5];
  const float* w_fg = (const float*)d_in[6];
  const float* b_fg = (const float*)d_in[7];
  const float* w_mo = (const float*)d_in[8];
  const float* b_mo = (const float*)d_in[9];
  const float* w1_0 = (const float*)d_in[10];
  const float* b1_0 = (const float*)d_in[11];
  const float* w2_0 = (const float*)d_in[12];
  const float* b2_0 = (const float*)d_in[13];
  const float* m_w1_0 = (const float*)d_in[14];
  const float* m_b1_0 = (const float*)d_in[15];
  const float* m_w2_0 = (const float*)d_in[16];
  const float* m_b2_0 = (const float*)d_in[17];
  const float* w1_1 = (const float*)d_in[18];
  const float* b1_1 = (const float*)d_in[19];
  const float* w2_1 = (const float*)d_in[20];
  const float* b2_1 = (const float*)d_in[21];
  const float* m_w1_1 = (const float*)d_in[22];
  const float* m_b1_1 = (const float*)d_in[23];
  const float* m_w2_1 = (const float*)d_in[24];
  const float* m_b2_1 = (const float*)d_in[25];

  float* wsf = (float*)d_ws;
  unsigned long long* red = (unsigned long long*)d_ws;   // 98304 B of slots
  float* qbuf = wsf + 32768;
  float* kbuf = qbuf + NB*SEQ*HD;
  float* vbuf = kbuf + NB*SEQ*HD;
  float* thb  = vbuf + NB*SEQ*HD;
  float* alb  = thb + NB*SEQ;
  float* etb  = alb + NB*SEQ;
  // ws re-poisoned to 0xAA each launch; 0xAAAAAAAA is never a valid seq tag.

  qkv_kernel<<<dim3(NB*SEQ/TOK), dim3(HD), 0, stream>>>(
      x, Wq, Wk, Wv, w_lr, b_lr, w_fg, b_fg, w_mo, b_mo,
      qbuf, kbuf, vbuf, thb, alb, etb);

  scan_kernel<<<dim3(NB*NWG), dim3(512), 0, stream>>>(
      w1_0, b1_0, w2_0, b2_0, m_w1_0, m_b1_0, m_w2_0, m_b2_0,
      w1_1, b1_1, w2_1, b2_1, m_w1_1, m_b1_1, m_w2_1, m_b2_1,
      qbuf, kbuf, vbuf, thb, alb, etb,
      red, (float*)d_out);
}

// Round 7
// 1786.374 us; speedup vs baseline: 2.9143x; 1.0817x over previous
//
#include <hip/hip_runtime.h>

// NeuralMemory scan: B=4, S=256, H=128, EXP=2, DEPTH=2.
// Round 17: R16 base (verified: scan steady 1816us, bench 1932, absmax
// 4.8e-7) + ONE change: XCD co-location of each batch's 4 workgroups.
// Budget at R16: 7.07us/step = ~2.0 VALU + ~1 barriers/LDS + ~4 in 3 poll
// RTs (B shadowed, 1 and 2 naked ~1.3us each). RT ~3000cy = cross-XCD L2
// miss (~900cy/dependent retry x ~1.5-2 retries): bids {b,b+4,b+8,b+12}
// under de-facto XCD=bid%8 round-robin span 2 XCDs per batch.
// Fix: launch 32 blocks; rb -> XCD rb&7; blocks with (rb&7)>=4 exit;
// batch=rb&7, wg=rb>>3 -> batch b's WGs = bids {b,b+8,b+16,b+24}, all
// same XCD -> polls hit the shared per-XCD L2 (~200-300cy).
// Correctness does NOT depend on the mapping (only speed); if the
// round-robin assumption is wrong, perf ~ unchanged.
// Predicted: scan 1816 -> ~1200-1450 if mapping holds; unchanged if not.
// Also learned (R16): bench-scan gap ~116us is harness overhead (reset
// memsets), stable across 3 qkv versions -> qkv untouched from here.

constexpr int HD  = 128;   // H
constexpr int SEQ = 256;   // S
constexpr int NB  = 4;     // B
constexpr int ED  = 256;   // H*EXP
constexpr int CW  = 64;    // hidden units per WG per layer (ED/NWG)
constexpr int NWG = 4;     // workgroups per batch
constexpr int TOK = 8;     // tokens per qkv block

// fast sigmoid: v_exp_f32 computes 2^x, so 1/(1+e^-x) = rcp(1 + 2^(-x*log2e)).
__device__ __forceinline__ float sigm(float x){
  float e;
  asm("v_exp_f32 %0, %1" : "=v"(e) : "v"(x * -1.44269504088896f));
  float r;
  asm("v_rcp_f32 %0, %1" : "=v"(r) : "v"(1.0f + e));
  return r;
}

// DPP-add helper: x + perm(x); ctrl must be a compile-time constant.
template<int CTRL>
__device__ __forceinline__ float dpp_add(float x){
  int y = __builtin_amdgcn_update_dpp(0, __float_as_int(x), CTRL, 0xF, 0xF, true);
  return x + __int_as_float(y);
}
// sum over each 32-lane group (bits 0..4), result in all lanes.
__device__ __forceinline__ float red32(float x){
  x = dpp_add<0xB1>(x);
  x = dpp_add<0x4E>(x);
  x = dpp_add<0x141>(x);
  x = dpp_add<0x140>(x);
  x += __int_as_float(__builtin_amdgcn_ds_swizzle(__float_as_int(x), 0x401F));
  return x;
}
__device__ __forceinline__ float red64(float x){
  x = red32(x);
  x += __shfl_xor(x, 32, 64);
  return x;
}

// ---------------- kernel 1: q/k/v + gate scalars (8 tokens/block) ----------------
__global__ __launch_bounds__(128) void qkv_kernel(
    const float* __restrict__ x,
    const float* __restrict__ Wq, const float* __restrict__ Wk, const float* __restrict__ Wv,
    const float* __restrict__ w_lr, const float* __restrict__ b_lr,
    const float* __restrict__ w_fg, const float* __restrict__ b_fg,
    const float* __restrict__ w_mo, const float* __restrict__ b_mo,
    float* __restrict__ qb, float* __restrict__ kb, float* __restrict__ vb,
    float* __restrict__ thb, float* __restrict__ alb, float* __restrict__ etb)
{
  const int t0 = blockIdx.x * TOK;    // first flattened token (b*SEQ+s)
  const int o  = threadIdx.x;         // 0..127
  __shared__ float xl[TOK][HD];
  __shared__ float red2[2][8];        // cross-wave partials

  #pragma unroll
  for (int tt=0; tt<TOK; ++tt)
    xl[tt][o] = x[(size_t)(t0+tt)*HD + o];
  const float wl = w_lr[o], wf = w_fg[o], wm = w_mo[o];
  const float blr = b_lr[0], bfg = b_fg[0], bmo = b_mo[0];
  __syncthreads();

  float aq[TOK], ak[TOK], av[TOK];
  #pragma unroll
  for (int tt=0; tt<TOK; ++tt){ aq[tt]=0.f; ak[tt]=0.f; av[tt]=0.f; }
  for (int i=0; i<HD; i+=4){
    float wq0=Wq[(i+0)*HD+o], wk0=Wk[(i+0)*HD+o], wv0=Wv[(i+0)*HD+o];
    float wq1=Wq[(i+1)*HD+o], wk1=Wk[(i+1)*HD+o], wv1=Wv[(i+1)*HD+o];
    float wq2=Wq[(i+2)*HD+o], wk2=Wk[(i+2)*HD+o], wv2=Wv[(i+2)*HD+o];
    float wq3=Wq[(i+3)*HD+o], wk3=Wk[(i+3)*HD+o], wv3=Wv[(i+3)*HD+o];
    #pragma unroll
    for (int tt=0; tt<TOK; ++tt){
      float4 xv = *reinterpret_cast<const float4*>(&xl[tt][i]);
      aq[tt]=fmaf(xv.x,wq0,aq[tt]); ak[tt]=fmaf(xv.x,wk0,ak[tt]); av[tt]=fmaf(xv.x,wv0,av[tt]);
      aq[tt]=fmaf(xv.y,wq1,aq[tt]); ak[tt]=fmaf(xv.y,wk1,ak[tt]); av[tt]=fmaf(xv.y,wv1,av[tt]);
      aq[tt]=fmaf(xv.z,wq2,aq[tt]); ak[tt]=fmaf(xv.z,wk2,ak[tt]); av[tt]=fmaf(xv.z,wv2,av[tt]);
      aq[tt]=fmaf(xv.w,wq3,aq[tt]); ak[tt]=fmaf(xv.w,wk3,ak[tt]); av[tt]=fmaf(xv.w,wv3,av[tt]);
    }
  }
  #pragma unroll
  for (int tt=0; tt<TOK; ++tt){
    const size_t idx = (size_t)(t0+tt);
    float a_q=aq[tt], a_k=ak[tt], a_v=av[tt];
    float sq_ = a_q*sigm(a_q);
    float sk_ = a_k*sigm(a_k);
    float sv_ = a_v*sigm(a_v);
    float xo = xl[tt][o];
    float p0 = red64(sq_*sq_);
    float p1 = red64(sk_*sk_);
    float p2 = red64(xo*wl);
    float p3 = red64(xo*wf);
    float p4 = red64(xo*wm);
    if ((o&63)==0){
      int w = o>>6;
      red2[w][0]=p0; red2[w][1]=p1; red2[w][2]=p2; red2[w][3]=p3; red2[w][4]=p4;
    }
    __syncthreads();
    float nq = red2[0][0]+red2[1][0];
    float nk = red2[0][1]+red2[1][1];
    qb[idx*HD+o] = sq_ / fmaxf(sqrtf(nq), 1e-12f);
    kb[idx*HD+o] = sk_ / fmaxf(sqrtf(nk), 1e-12f);
    vb[idx*HD+o] = sv_;
    if (o==0){
      float dl = red2[0][2]+red2[1][2];
      float df = red2[0][3]+red2[1][3];
      float dm = red2[0][4]+red2[1][4];
      thb[idx] = sigm(dl + blr) * 0.01f;   // MAX_LR
      alb[idx] = sigm(df + bfg);
      etb[idx] = sigm(dm + bmo);
    }
    __syncthreads();   // red2 reuse next token
  }
}

// ---------------- kernel 2: the sequential scan ----------------
__global__ __launch_bounds__(512, 1) void scan_kernel(
    const float* __restrict__ w1_0g, const float* __restrict__ b1_0g,
    const float* __restrict__ w2_0g, const float* __restrict__ b2_0g,
    const float* __restrict__ mw1_0g, const float* __restrict__ mb1_0g,
    const float* __restrict__ mw2_0g, const float* __restrict__ mb2_0g,
    const float* __restrict__ w1_1g, const float* __restrict__ b1_1g,
    const float* __restrict__ w2_1g, const float* __restrict__ b2_1g,
    const float* __restrict__ mw1_1g, const float* __restrict__ mb1_1g,
    const float* __restrict__ mw2_1g, const float* __restrict__ mb2_1g,
    const float* __restrict__ qbuf, const float* __restrict__ kbuf, const float* __restrict__ vbuf,
    const float* __restrict__ thb, const float* __restrict__ alb, const float* __restrict__ etb,
    unsigned long long* __restrict__ red, float* __restrict__ out)
{
  // XCD co-location: de-facto mapping is XCD = blockIdx % 8. Launch 32
  // blocks; keep only (rb&7) < NB. Batch b's 4 WGs are bids {b,b+8,b+16,
  // b+24} -> all on XCD b -> poll slots stay in that XCD's L2.
  const int rb  = blockIdx.x;
  const int b   = rb & 7;      // candidate batch = XCD id
  if (b >= NB) return;         // XCDs 4..7: no work
  const int wg  = rb >> 3;     // 0..3 within batch
  const int tid = threadIdx.x;
  const int iG  = tid & 31;    // i-group (w1) / o-group (w2)
  const int jG  = tid >> 5;    // j-group 0..15
  const int i0  = iG*4;
  const int j0  = jG*4;
  const int c0  = wg*CW;

  __shared__ float pw1L[2][16][512];   // 64 KB p0 (w1), [plane][tid]
  __shared__ float pw2L[2][16][512];   // 64 KB p0 (w2)
  __shared__ float h1k[HD], h1q[HD], h2k[HD], gh1[HD];
  __shared__ float redbuf[8][256];
  __shared__ float b1p[2][CW], b1n[2][CW], b2p[2][32], b2n[2][32];

  // actual weights n = p0*(1-a) + m, carried in registers
  float nw1[2][16], nw2[2][16];
  {
    const float* w1s[2]  = {w1_0g,  w1_1g};
    const float* mw1s[2] = {mw1_0g, mw1_1g};
    const float* w2s[2]  = {w2_0g,  w2_1g};
    const float* mw2s[2] = {mw2_0g, mw2_1g};
    #pragma unroll
    for (int l=0;l<2;l++){
      #pragma unroll
      for (int jj=0;jj<4;jj++){
        #pragma unroll
        for (int ii=0;ii<4;ii++){
          int gi1 = (i0+ii)*ED + (c0+j0+jj);
          float p1 = w1s[l][gi1];
          pw1L[l][jj*4+ii][tid] = p1;
          nw1[l][jj*4+ii] = p1 + mw1s[l][gi1];   // n_{-1} = p0 + m0
          int gi2 = (c0+j0+jj)*HD + (i0+ii);
          float p2 = w2s[l][gi2];
          pw2L[l][jj*4+ii][tid] = p2;
          nw2[l][jj*4+ii] = p2 + mw2s[l][gi2];
        }
      }
    }
  }
  if (tid < CW){
    float p0a = b1_0g[c0+tid], p1a = b1_1g[c0+tid];
    b1p[0][tid] = p0a; b1n[0][tid] = p0a + mb1_0g[c0+tid];
    b1p[1][tid] = p1a; b1n[1][tid] = p1a + mb1_1g[c0+tid];
  } else if (tid < CW+32){
    int oo = tid - CW;
    float p0a = b2_0g[wg*32+oo], p1a = b2_1g[wg*32+oo];
    b2p[0][oo] = p0a; b2n[0][oo] = p0a + mb2_0g[wg*32+oo];
    b2p[1][oo] = p1a; b2n[1][oo] = p1a + mb2_1g[wg*32+oo];
  }

  auto pubstore = [&](int type, unsigned seq, int idx, float val){
    unsigned long long* p = red + (((b*3+type)*NWG + wg)*256 + idx);
    unsigned long long pk = ((unsigned long long)seq << 32) |
                            (unsigned long long)__float_as_uint(val);
    __hip_atomic_store(p, pk, __ATOMIC_RELAXED, __HIP_MEMORY_SCOPE_AGENT);
  };
  auto pollacc = [&](int type, unsigned seq, int idx, float own)->float{
    unsigned long long* base = red + ((b*3+type)*NWG)*256;
    const int wA=((wg+1)&3)*256+idx, wB=((wg+2)&3)*256+idx, wC=((wg+3)&3)*256+idx;
    unsigned long long vA = __hip_atomic_load(base+wA, __ATOMIC_RELAXED, __HIP_MEMORY_SCOPE_AGENT);
    unsigned long long vB = __hip_atomic_load(base+wB, __ATOMIC_RELAXED, __HIP_MEMORY_SCOPE_AGENT);
    unsigned long long vC = __hip_atomic_load(base+wC, __ATOMIC_RELAXED, __HIP_MEMORY_SCOPE_AGENT);
    float s = own; unsigned got = 0;
    while (got != 7u){
      if (!(got&1u)){
        if ((unsigned)(vA>>32)==seq){ s += __uint_as_float((unsigned)vA); got|=1u; }
        else vA = __hip_atomic_load(base+wA, __ATOMIC_RELAXED, __HIP_MEMORY_SCOPE_AGENT);
      }
      if (!(got&2u)){
        if ((unsigned)(vB>>32)==seq){ s += __uint_as_float((unsigned)vB); got|=2u; }
        else vB = __hip_atomic_load(base+wB, __ATOMIC_RELAXED, __HIP_MEMORY_SCOPE_AGENT);
      }
      if (!(got&4u)){
        if ((unsigned)(vC>>32)==seq){ s += __uint_as_float((unsigned)vC); got|=4u; }
        else vC = __hip_atomic_load(base+wC, __ATOMIC_RELAXED, __HIP_MEMORY_SCOPE_AGENT);
      }
    }
    return s;
  };

  // loop-carried per-thread state
  float u1_r[4], s1_r[4], sg1_r[4], u2_r[4], s2_r[4], sg2_r[4], h1k_r[4], v_r[4], vc_r = 0.f;
  float kprev4[4];   // k_t (this step's grad key), i0-range

  // forward from biased layer-0 pre-activations uq/uk.
  // ro = F1 residual (tid<128: q_t[tid]; 128..255: k_{t+1}[tid-128]).
  auto fwdFromU = [&](int t, bool writeOut, unsigned seq,
                      const float* uq, const float* uk, float ro){
    float sq1q[4];
    #pragma unroll
    for (int jj=0;jj<4;jj++){
      float vq = uq[jj], vk = uk[jj];
      u1_r[jj]=vk;
      float sgk = sigm(vk);
      sg1_r[jj]=sgk; s1_r[jj]=vk*sgk;
      sq1q[jj]=vq*sigm(vq);
    }
    // ---- layer0 out partials (nw2[0] = n_t, updated before call) ----
    float oq[4]={0,0,0,0}, ok[4]={0,0,0,0};
    #pragma unroll
    for (int jj=0;jj<4;jj++){
      #pragma unroll
      for (int oo=0;oo<4;oo++){
        float w = nw2[0][jj*4+oo];
        oq[oo] = fmaf(sq1q[jj], w, oq[oo]);
        ok[oo] = fmaf(s1_r[jj], w, ok[oo]);
      }
    }
    #pragma unroll
    for (int oo=0;oo<4;oo++){
      oq[oo] += __shfl_xor(oq[oo], 32, 64);
      ok[oo] += __shfl_xor(ok[oo], 32, 64);
    }
    if (!(tid & 32)){
      int wv = tid>>6;
      #pragma unroll
      for (int oo=0;oo<4;oo++){
        redbuf[wv][i0+oo]     = oq[oo];
        redbuf[wv][128+i0+oo] = ok[oo];
      }
    }
    __syncthreads();                       // S4
    if (tid < 256){
      float p=0.f;
      #pragma unroll
      for (int w_=0; w_<8; w_++) p += redbuf[w_][tid];
      int o = tid & 127;
      if (o >= wg*32 && o < wg*32+32)
        p += b2n[0][o-wg*32];
      pubstore(1, seq, tid, p);
      float s0 = ro + pollacc(1, seq, tid, p);
      if (tid<128) h1q[o]=s0; else h1k[o]=s0;
    }
    __syncthreads();                       // S5
    // ---- layer1 u ----
    float aq2[4]={0,0,0,0}, ak2[4]={0,0,0,0};
    #pragma unroll
    for (int ii=0;ii<4;ii++){
      float qi = h1q[i0+ii], ki = h1k[i0+ii];
      h1k_r[ii] = ki;
      #pragma unroll
      for (int jj=0;jj<4;jj++){
        float w = nw1[1][jj*4+ii];
        aq2[jj] = fmaf(qi, w, aq2[jj]);
        ak2[jj] = fmaf(ki, w, ak2[jj]);
      }
    }
    #pragma unroll
    for (int jj=0;jj<4;jj++){
      aq2[jj] = red32(aq2[jj]);
      ak2[jj] = red32(ak2[jj]);
    }
    float sq2q[4];
    #pragma unroll
    for (int jj=0;jj<4;jj++){
      float bb = b1n[1][j0+jj];
      float vq = aq2[jj]+bb, vk = ak2[jj]+bb;
      u2_r[jj]=vk;
      float sgk = sigm(vk);
      sg2_r[jj]=sgk; s2_r[jj]=vk*sgk;
      sq2q[jj]=vq*sigm(vq);
    }
    // ---- layer1 out partials ----
    #pragma unroll
    for (int oo=0;oo<4;oo++){ oq[oo]=0.f; ok[oo]=0.f; }
    #pragma unroll
    for (int jj=0;jj<4;jj++){
      #pragma unroll
      for (int oo=0;oo<4;oo++){
        float w = nw2[1][jj*4+oo];
        oq[oo] = fmaf(sq2q[jj], w, oq[oo]);
        ok[oo] = fmaf(s2_r[jj], w, ok[oo]);
      }
    }
    #pragma unroll
    for (int oo=0;oo<4;oo++){
      oq[oo] += __shfl_xor(oq[oo], 32, 64);
      ok[oo] += __shfl_xor(ok[oo], 32, 64);
    }
    if (!(tid & 32)){
      int wv = tid>>6;
      #pragma unroll
      for (int oo=0;oo<4;oo++){
        redbuf[wv][i0+oo]     = oq[oo];
        redbuf[wv][128+i0+oo] = ok[oo];
      }
    }
    __syncthreads();                       // S6
    if (tid < 256){
      float p=0.f;
      #pragma unroll
      for (int w_=0; w_<8; w_++) p += redbuf[w_][tid];
      int o = tid & 127;
      if (o >= wg*32 && o < wg*32+32)
        p += b2n[1][o-wg*32];
      pubstore(2, seq, tid, p);
      float s0 = ((tid<128) ? h1q[o] : h1k[o]) + pollacc(2, seq, tid, p);
      if (tid<128){
        if (writeOut && o >= wg*32 && o < wg*32+32)
          out[((size_t)(b*SEQ + t))*HD + o] = s0;
      } else {
        h2k[o] = s0;
      }
    }
  };

  // ---- prologue: forward k_0 with n_{-1} = p0 + m0 (m0=0 pristine) ----
  {
    #pragma unroll
    for (int ii=0;ii<4;ii++){
      kprev4[ii] = kbuf[((size_t)b*SEQ + 0)*HD + i0+ii];
      v_r[ii]    = vbuf[((size_t)b*SEQ + 0)*HD + i0+ii];
    }
    if (tid < HD) vc_r = vbuf[((size_t)b*SEQ + 0)*HD + tid];
    float ro0 = 0.f;
    if (tid >= 128 && tid < 256)
      ro0 = kbuf[((size_t)b*SEQ + 0)*HD + (tid-128)];
    __syncthreads();   // init (LDS p0/biases) visible
    float ak0[4]={0,0,0,0};
    #pragma unroll
    for (int ii=0;ii<4;ii++){
      float ki = kprev4[ii];
      #pragma unroll
      for (int jj=0;jj<4;jj++)
        ak0[jj] = fmaf(ki, nw1[0][jj*4+ii], ak0[jj]);
    }
    #pragma unroll
    for (int jj=0;jj<4;jj++) ak0[jj] = red32(ak0[jj]);
    float uq0[4], uk0[4];
    #pragma unroll
    for (int jj=0;jj<4;jj++){
      float bb = b1n[0][j0+jj];
      uq0[jj] = bb;              // q-path = 0 vector (discarded)
      uk0[jj] = ak0[jj] + bb;
    }
    fwdFromU(0, false, 1u, uq0, uk0, ro0);
  }

  float dPrev = 1.f;   // 1 - alpha_{-1}
  for (int t=0; t<SEQ; ++t){
    const int tn = (t < SEQ-1) ? t+1 : SEQ-1;
    // ---- early global loads: q_t, k_{t+1} (hidden under S1 + backward) ----
    float qv4[4], kv4[4];
    #pragma unroll
    for (int ii=0;ii<4;ii++){
      qv4[ii] = qbuf[((size_t)b*SEQ + t )*HD + i0+ii];
      kv4[ii] = kbuf[((size_t)b*SEQ + tn)*HD + i0+ii];
    }
    float ro = 0.f;
    if (tid < 128)      ro = qbuf[((size_t)b*SEQ + t )*HD + tid];
    else if (tid < 256) ro = kbuf[((size_t)b*SEQ + tn)*HD + (tid-128)];
    const float th = thb[b*SEQ+t];
    const float al = alb[b*SEQ+t];
    const float et = etb[b*SEQ+t];
    const float nth = -th;
    const float dcur = 1.f - al;
    const float cP = dcur - et*dPrev;
    __syncthreads();                       // S1: h2k from prev fwd visible
    // ---- g2v, gu2 (weights n_{t-1}) ----
    float g2v_r[4];
    #pragma unroll
    for (int ii=0;ii<4;ii++) g2v_r[ii] = 0.015625f*(h2k[i0+ii] - v_r[ii]);
    float acc[4]={0,0,0,0};
    #pragma unroll
    for (int oo=0;oo<4;oo++){
      float go = g2v_r[oo];
      #pragma unroll
      for (int jj=0;jj<4;jj++)
        acc[jj] = fmaf(go, nw2[1][jj*4+oo], acc[jj]);
    }
    #pragma unroll
    for (int jj=0;jj<4;jj++) acc[jj] = red32(acc[jj]);
    float gu2r[4];
    #pragma unroll
    for (int jj=0;jj<4;jj++){
      float u=u2_r[jj]; float sg=sg2_r[jj];          // cached from fwd
      gu2r[jj] = acc[jj]*sg*fmaf(u, 1.f-sg, 1.f);
    }
    // ---- gh1 partial ----
    float a2[4]={0,0,0,0};
    #pragma unroll
    for (int jj=0;jj<4;jj++){
      float gj = gu2r[jj];
      #pragma unroll
      for (int ii=0;ii<4;ii++)
        a2[ii] = fmaf(gj, nw1[1][jj*4+ii], a2[ii]);
    }
    #pragma unroll
    for (int ii=0;ii<4;ii++) a2[ii] += __shfl_xor(a2[ii], 32, 64);
    if (!(tid & 32)){
      int wv = tid>>6;
      #pragma unroll
      for (int ii=0;ii<4;ii++) redbuf[wv][i0+ii] = a2[ii];
    }
    __syncthreads();                       // S2
    const unsigned seqB = (unsigned)(t+1);
    float pB = 0.f, g2vc = 0.f;
    if (tid < HD){
      #pragma unroll
      for (int w_=0;w_<8;w_++) pB += redbuf[w_][tid];
      pubstore(0, seqB, tid, pB);          // publish ASAP
      g2vc = 0.015625f*(h2k[tid] - vc_r);
    }
    // ---- B-poll shadow: layer-1 n-updates + v prefetch ----
    {
      float tg2[4], tv2[4];
      #pragma unroll
      for (int jj=0;jj<4;jj++) tg2[jj] = nth*gu2r[jj];
      #pragma unroll
      for (int ii=0;ii<4;ii++) tv2[ii] = nth*g2v_r[ii];
      #pragma unroll
      for (int jj=0;jj<4;jj++){
        float g2jt = tg2[jj], s2j = s2_r[jj];
        #pragma unroll
        for (int ii=0;ii<4;ii++){
          int e = jj*4+ii;
          nw1[1][e] = fmaf(et, nw1[1][e],
                           fmaf(cP, pw1L[1][e][tid], h1k_r[ii]*g2jt));
          nw2[1][e] = fmaf(et, nw2[1][e],
                           fmaf(cP, pw2L[1][e][tid], s2j*tv2[ii]));
        }
      }
      if (iG==0){
        #pragma unroll
        for (int jj=0;jj<4;jj++)
          b1n[1][j0+jj] = fmaf(et, b1n[1][j0+jj],
                               fmaf(cP, b1p[1][j0+jj], tg2[jj]));
      }
      if (jG==0 && iG>=wg*8 && iG<wg*8+8){
        #pragma unroll
        for (int ii=0;ii<4;ii++)
          b2n[1][i0+ii-wg*32] = fmaf(et, b2n[1][i0+ii-wg*32],
                                     fmaf(cP, b2p[1][i0+ii-wg*32], tv2[ii]));
      }
    }
    // prefetch v_{t+1} (old v consumed above)
    #pragma unroll
    for (int ii=0;ii<4;ii++)
      v_r[ii] = vbuf[((size_t)b*SEQ + tn)*HD + i0+ii];
    if (tid < HD) vc_r = vbuf[((size_t)b*SEQ + tn)*HD + tid];
    // ---- poll B ----
    if (tid < HD)
      gh1[tid] = g2vc + pollacc(0, seqB, tid, pB);
    __syncthreads();                       // S3
    // ---- gu1 (weights nw2[0] = n_{t-1}) ----
    float gh1_r[4];
    #pragma unroll
    for (int ii=0;ii<4;ii++) gh1_r[ii] = gh1[i0+ii];
    #pragma unroll
    for (int jj=0;jj<4;jj++) acc[jj]=0.f;
    #pragma unroll
    for (int oo=0;oo<4;oo++){
      float go = gh1_r[oo];
      #pragma unroll
      for (int jj=0;jj<4;jj++)
        acc[jj] = fmaf(go, nw2[0][jj*4+oo], acc[jj]);
    }
    #pragma unroll
    for (int jj=0;jj<4;jj++) acc[jj] = red32(acc[jj]);
    float gu1r[4];
    #pragma unroll
    for (int jj=0;jj<4;jj++){
      float u=u1_r[jj]; float sg=sg1_r[jj];          // cached from fwd
      gu1r[jj] = acc[jj]*sg*fmaf(u, 1.f-sg, 1.f);
    }
    // ---- layer-0 n-updates (LDS p0 reads) ----
    {
      float tg1[4], tv0[4];
      #pragma unroll
      for (int jj=0;jj<4;jj++) tg1[jj] = nth*gu1r[jj];
      #pragma unroll
      for (int ii=0;ii<4;ii++) tv0[ii] = nth*gh1_r[ii];
      #pragma unroll
      for (int jj=0;jj<4;jj++){
        float g1jt = tg1[jj], s1j = s1_r[jj];
        #pragma unroll
        for (int ii=0;ii<4;ii++){
          int e = jj*4+ii;
          nw1[0][e] = fmaf(et, nw1[0][e],
                           fmaf(cP, pw1L[0][e][tid], kprev4[ii]*g1jt));
          nw2[0][e] = fmaf(et, nw2[0][e],
                           fmaf(cP, pw2L[0][e][tid], s1j*tv0[ii]));
        }
      }
      if (iG==0){
        #pragma unroll
        for (int jj=0;jj<4;jj++)
          b1n[0][j0+jj] = fmaf(et, b1n[0][j0+jj],
                               fmaf(cP, b1p[0][j0+jj], tg1[jj]));
      }
      if (jG==0 && iG>=wg*8 && iG<wg*8+8){
        #pragma unroll
        for (int ii=0;ii<4;ii++)
          b2n[0][i0+ii-wg*32] = fmaf(et, b2n[0][i0+ii-wg*32],
                                     fmaf(cP, b2p[0][i0+ii-wg*32], tv0[ii]));
      }
    }
    // ---- layer-0 dual u with updated n_t (register q/k inputs) ----
    float aq[4]={0,0,0,0}, ak[4]={0,0,0,0};
    #pragma unroll
    for (int ii=0;ii<4;ii++){
      float qi = qv4[ii], ki = kv4[ii];
      #pragma unroll
      for (int jj=0;jj<4;jj++){
        float w = nw1[0][jj*4+ii];
        aq[jj] = fmaf(qi, w, aq[jj]);
        ak[jj] = fmaf(ki, w, ak[jj]);
      }
    }
    #pragma unroll
    for (int jj=0;jj<4;jj++){
      aq[jj] = red32(aq[jj]);
      ak[jj] = red32(ak[jj]);
    }
    float uqf[4], ukf[4];
    #pragma unroll
    for (int jj=0;jj<4;jj++){
      float bb = b1n[0][j0+jj];   // wave-local RAW (writer iG==0 same wave)
      uqf[jj] = aq[jj] + bb;
      ukf[jj] = ak[jj] + bb;
    }
    #pragma unroll
    for (int ii=0;ii<4;ii++) kprev4[ii] = kv4[ii];   // k~ for next step
    dPrev = dcur;
    fwdFromU(t, true, (unsigned)(t+2), uqf, ukf, ro);
  }
}

extern "C" void kernel_launch(void* const* d_in, const int* in_sizes, int n_in,
                              void* d_out, int out_size, void* d_ws, size_t ws_size,
                              hipStream_t stream)
{
  (void)in_sizes; (void)n_in; (void)out_size; (void)ws_size;
  const float* x    = (const float*)d_in[0];
  const float* Wq   = (const float*)d_in[1];
  const float* Wk   = (const float*)d_in[2];
  const float* Wv   = (const float*)d_in[3];
  const float* w_lr = (const float*)d_in[4];
  const float* b_lr = (const float*)d_in[5];
  const float* w_fg = (const float*)d_in[6];
  const float* b_fg = (const float*)d_in[7];
  const float* w_mo = (const float*)d_in[8];
  const float* b_mo = (const float*)d_in[9];
  const float* w1_0 = (const float*)d_in[10];
  const float* b1_0 = (const float*)d_in[11];
  const float* w2_0 = (const float*)d_in[12];
  const float* b2_0 = (const float*)d_in[13];
  const float* m_w1_0 = (const float*)d_in[14];
  const float* m_b1_0 = (const float*)d_in[15];
  const float* m_w2_0 = (const float*)d_in[16];
  const float* m_b2_0 = (const float*)d_in[17];
  const float* w1_1 = (const float*)d_in[18];
  const float* b1_1 = (const float*)d_in[19];
  const float* w2_1 = (const float*)d_in[20];
  const float* b2_1 = (const float*)d_in[21];
  const float* m_w1_1 = (const float*)d_in[22];
  const float* m_b1_1 = (const float*)d_in[23];
  const float* m_w2_1 = (const float*)d_in[24];
  const float* m_b2_1 = (const float*)d_in[25];

  float* wsf = (float*)d_ws;
  unsigned long long* red = (unsigned long long*)d_ws;   // 98304 B of slots
  float* qbuf = wsf + 32768;
  float* kbuf = qbuf + NB*SEQ*HD;
  float* vbuf = kbuf + NB*SEQ*HD;
  float* thb  = vbuf + NB*SEQ*HD;
  float* alb  = thb + NB*SEQ;
  float* etb  = alb + NB*SEQ;
  // ws re-poisoned to 0xAA each launch; 0xAAAAAAAA is never a valid seq tag.

  qkv_kernel<<<dim3(NB*SEQ/TOK), dim3(HD), 0, stream>>>(
      x, Wq, Wk, Wv, w_lr, b_lr, w_fg, b_fg, w_mo, b_mo,
      qbuf, kbuf, vbuf, thb, alb, etb);

  // 32 blocks: 16 active (4 batches x 4 WGs, co-located per XCD), 16 exit.
  scan_kernel<<<dim3(4*NWG*2), dim3(512), 0, stream>>>(
      w1_0, b1_0, w2_0, b2_0, m_w1_0, m_b1_0, m_w2_0, m_b2_0,
      w1_1, b1_1, w2_1, b2_1, m_w1_1, m_b1_1, m_w2_1, m_b2_1,
      qbuf, kbuf, vbuf, thb, alb, etb,
      red, (float*)d_out);
}